// Round 1
// baseline (605.262 us; speedup 1.0000x reference)
//
#include <hip/hip_runtime.h>
#include <math.h>

#define NNODES 50000
#define NEDGES 800000
#define ET (NNODES + NEDGES)   // 850000 with self loops
#define SLOPE 0.2f
#define OUTD 40

// ======================= CSR build =======================

__global__ void k_count(const int* __restrict__ ei, int* __restrict__ deg){
  int e = blockIdx.x*256 + threadIdx.x;
  if (e >= ET) return;
  int dst = (e < NEDGES) ? ei[NEDGES + e] : (e - NEDGES);
  atomicAdd(&deg[dst], 1);
}

__global__ void k_bsum(const int* __restrict__ deg, int* __restrict__ bsum){
  int i = blockIdx.x*256 + threadIdx.x;
  int v = (i < NNODES) ? deg[i] : 0;
  for (int o = 1; o < 64; o <<= 1) v += __shfl_xor(v, o);
  __shared__ int ws[4];
  if ((threadIdx.x & 63) == 0) ws[threadIdx.x >> 6] = v;
  __syncthreads();
  if (threadIdx.x == 0) bsum[blockIdx.x] = ws[0] + ws[1] + ws[2] + ws[3];
}

__global__ void k_scanb(const int* __restrict__ bsum, int nb, int* __restrict__ boff){
  __shared__ int sm[256];
  int t = threadIdx.x;
  int v = (t < nb) ? bsum[t] : 0;
  sm[t] = v; __syncthreads();
  for (int d = 1; d < 256; d <<= 1){
    int x = (t >= d) ? sm[t - d] : 0;
    __syncthreads();
    sm[t] += x;
    __syncthreads();
  }
  if (t < nb) boff[t] = sm[t] - v;   // exclusive
}

__global__ void k_scanw(const int* __restrict__ deg, const int* __restrict__ boff,
                        int* __restrict__ rowptr){
  __shared__ int sm[256];
  int t = threadIdx.x, i = blockIdx.x*256 + t;
  int v = (i < NNODES) ? deg[i] : 0;
  sm[t] = v; __syncthreads();
  for (int d = 1; d < 256; d <<= 1){
    int x = (t >= d) ? sm[t - d] : 0;
    __syncthreads();
    sm[t] += x;
    __syncthreads();
  }
  if (i < NNODES) rowptr[i] = boff[blockIdx.x] + sm[t] - v;  // exclusive
}

__global__ void k_scatter(const int* __restrict__ ei, int* __restrict__ pos,
                          int* __restrict__ csr_src){
  int e = blockIdx.x*256 + threadIdx.x;
  if (e >= ET) return;
  int src, dst;
  if (e < NEDGES){ src = ei[e]; dst = ei[NEDGES + e]; }
  else           { src = dst = e - NEDGES; }
  int p = atomicAdd(&pos[dst], 1);
  csr_src[p] = src;
}

// ======================= GEMM (f32, dual-weight fused) =======================
// Computes O[n][c] = sum_k X[n][k]*W(c)[k][c'] + b(c)  for c in [0, NCols),
// where c < split -> (W0,b0,O0) col c, else (W1,b1,O1) col c-split.
// Tile: BM=128 x BN=64, BK=16, 256 threads, 8x4 micro-tile.

#define BM 128
#define BN 64
#define BK 16

__global__ __launch_bounds__(256) void k_gemm(
    const float* __restrict__ X, int ldx, int Kdim, int Nrows,
    const float* __restrict__ W0, const float* __restrict__ W1, int ldw,
    const float* __restrict__ b0, const float* __restrict__ b1, int split,
    float* __restrict__ O0, int ld0, float* __restrict__ O1, int ld1)
{
  __shared__ float As[BK][BM + 4];   // transposed: As[k][row]
  __shared__ float Bs[BK][BN];

  int t  = threadIdx.x;
  int tc = t & 15;      // col group: cols tc*4 .. tc*4+3
  int tr = t >> 4;      // row group: rows tr*8 .. tr*8+7
  int row0 = blockIdx.x * BM;
  int col0 = blockIdx.y * BN;

  // A staging map: thread -> (row, k-half)
  int arow = t >> 1;                 // 0..127
  int akh  = (t & 1) * 8;            // 0 or 8
  int agr  = min(row0 + arow, Nrows - 1);
  const float* Xp = X + (size_t)agr * ldx + akh;

  // B staging map: thread -> (k, 4 cols)
  int bk  = t >> 4;                  // 0..15
  int bc4 = (t & 15) * 4;
  int gcb = col0 + bc4;
  const float* Wp = (gcb < split) ? (W0 + gcb) : (W1 + (gcb - split));

  float acc[8][4];
  #pragma unroll
  for (int i = 0; i < 8; ++i)
    #pragma unroll
    for (int j = 0; j < 4; ++j) acc[i][j] = 0.f;

  for (int k0 = 0; k0 < Kdim; k0 += BK){
    float4 av0 = *(const float4*)(Xp + k0);
    float4 av1 = *(const float4*)(Xp + k0 + 4);
    float4 bv  = *(const float4*)(Wp + (size_t)(k0 + bk) * ldw);
    __syncthreads();   // previous iteration's reads done
    As[akh+0][arow] = av0.x; As[akh+1][arow] = av0.y;
    As[akh+2][arow] = av0.z; As[akh+3][arow] = av0.w;
    As[akh+4][arow] = av1.x; As[akh+5][arow] = av1.y;
    As[akh+6][arow] = av1.z; As[akh+7][arow] = av1.w;
    *(float4*)&Bs[bk][bc4] = bv;
    __syncthreads();
    #pragma unroll
    for (int kk = 0; kk < BK; ++kk){
      float4 a0 = *(const float4*)&As[kk][tr*8];
      float4 a1 = *(const float4*)&As[kk][tr*8 + 4];
      float4 b  = *(const float4*)&Bs[kk][tc*4];
      float a[8] = {a0.x,a0.y,a0.z,a0.w,a1.x,a1.y,a1.z,a1.w};
      float bb[4] = {b.x,b.y,b.z,b.w};
      #pragma unroll
      for (int i = 0; i < 8; ++i)
        #pragma unroll
        for (int j = 0; j < 4; ++j) acc[i][j] += a[i]*bb[j];
    }
  }

  // epilogue: bias + store
  int gcc = col0 + tc*4;
  const float* bp = (gcc < split) ? (b0 + gcc) : (b1 + (gcc - split));
  float4 bias4 = *(const float4*)bp;
  float* Ob; int ldO, cc;
  if (gcc < split){ Ob = O0; ldO = ld0; cc = gcc; }
  else            { Ob = O1; ldO = ld1; cc = gcc - split; }
  #pragma unroll
  for (int i = 0; i < 8; ++i){
    int gr = row0 + tr*8 + i;
    if (gr < Nrows){
      float4 v = make_float4(acc[i][0] + bias4.x, acc[i][1] + bias4.y,
                             acc[i][2] + bias4.z, acc[i][3] + bias4.w);
      *(float4*)(Ob + (size_t)gr * ldO + cc) = v;
    }
  }
}

// ======================= Layer 1 aggregation (fused softmax) =================
// One wave per dst node. D=128 (4 heads x 32). Lane l owns channels 2l,2l+1.
__global__ __launch_bounds__(256) void k_agg1(
    const float* __restrict__ xl, const float* __restrict__ xr,
    const int* __restrict__ rowptr, const int* __restrict__ deg,
    const int* __restrict__ csr, const float* __restrict__ att,
    const float* __restrict__ bias, float* __restrict__ hout)
{
  int node = blockIdx.x*4 + (threadIdx.x >> 6);
  if (node >= NNODES) return;
  int l  = threadIdx.x & 63;
  int h  = l >> 4;
  int li = l & 15;
  int c0 = 2*l;

  float a0 = att[h*32 + 2*li], a1 = att[h*32 + 2*li + 1];
  float2 xrv = *(const float2*)(xr + (size_t)node*128 + c0);

  float m = -INFINITY, s = 0.f, acc0 = 0.f, acc1 = 0.f;
  int start = rowptr[node], cnt = deg[node];
  for (int i = 0; i < cnt; ++i){
    int src = csr[start + i];
    float2 xlv = *(const float2*)(xl + (size_t)src*128 + c0);
    float g0 = xlv.x + xrv.x; g0 = g0 > 0.f ? g0 : SLOPE*g0;
    float g1 = xlv.y + xrv.y; g1 = g1 > 0.f ? g1 : SLOPE*g1;
    float p = g0*a0 + g1*a1;
    p += __shfl_xor(p, 1); p += __shfl_xor(p, 2);
    p += __shfl_xor(p, 4); p += __shfl_xor(p, 8);
    float mn  = fmaxf(m, p);
    float wgt = __expf(p - mn);
    float sc  = __expf(m - mn);
    s = s*sc + wgt;
    acc0 = acc0*sc + wgt*xlv.x;
    acc1 = acc1*sc + wgt*xlv.y;
    m = mn;
  }
  float inv = 1.f/(s + 1e-16f);
  float o0 = acc0*inv + bias[c0];
  float o1 = acc1*inv + bias[c0 + 1];
  o0 = o0 > 0.f ? o0 : (__expf(o0) - 1.f);   // ELU
  o1 = o1 > 0.f ? o1 : (__expf(o1) - 1.f);
  *(float2*)(hout + (size_t)node*128 + c0) = make_float2(o0, o1);
}

// ======================= Layer 2 aggregation (head-mean) =====================
// One wave per dst node. D=160 (4 heads x 40). Lane (h,li) owns channels
// h*40 + {li, 16+li, 32+li(li<8)}. Head-mean via shfl over lane groups.
__global__ __launch_bounds__(256) void k_agg2(
    const float* __restrict__ xl, const float* __restrict__ xr,
    const int* __restrict__ rowptr, const int* __restrict__ deg,
    const int* __restrict__ csr, const float* __restrict__ att,
    const float* __restrict__ bias, float* __restrict__ out)
{
  int node = blockIdx.x*4 + (threadIdx.x >> 6);
  if (node >= NNODES) return;
  int l  = threadIdx.x & 63;
  int h  = l >> 4;
  int li = l & 15;
  bool has3 = (li < 8);
  int rb = h*OUTD;

  float a0 = att[rb + li], a1 = att[rb + 16 + li];
  float a2 = has3 ? att[rb + 32 + li] : 0.f;
  const float* xrp = xr + (size_t)node*160 + rb;
  float r0 = xrp[li], r1 = xrp[16 + li];
  float r2 = has3 ? xrp[32 + li] : 0.f;

  float m = -INFINITY, s = 0.f, acc0 = 0.f, acc1 = 0.f, acc2 = 0.f;
  int start = rowptr[node], cnt = deg[node];
  for (int i = 0; i < cnt; ++i){
    int src = csr[start + i];
    const float* xp = xl + (size_t)src*160 + rb;
    float v0 = xp[li], v1 = xp[16 + li];
    float v2 = has3 ? xp[32 + li] : 0.f;
    float g0 = v0 + r0; g0 = g0 > 0.f ? g0 : SLOPE*g0;
    float g1 = v1 + r1; g1 = g1 > 0.f ? g1 : SLOPE*g1;
    float g2 = v2 + r2; g2 = g2 > 0.f ? g2 : SLOPE*g2;
    float p = g0*a0 + g1*a1 + g2*a2;
    p += __shfl_xor(p, 1); p += __shfl_xor(p, 2);
    p += __shfl_xor(p, 4); p += __shfl_xor(p, 8);
    float mn  = fmaxf(m, p);
    float wgt = __expf(p - mn);
    float sc  = __expf(m - mn);
    s = s*sc + wgt;
    acc0 = acc0*sc + wgt*v0;
    acc1 = acc1*sc + wgt*v1;
    acc2 = acc2*sc + wgt*v2;
    m = mn;
  }
  float inv = 1.f/(s + 1e-16f);
  float o0 = acc0*inv, o1 = acc1*inv, o2 = acc2*inv;
  o0 += __shfl_xor(o0, 16); o0 += __shfl_xor(o0, 32);
  o1 += __shfl_xor(o1, 16); o1 += __shfl_xor(o1, 32);
  o2 += __shfl_xor(o2, 16); o2 += __shfl_xor(o2, 32);
  if (l < 16){
    float* op = out + (size_t)node*OUTD;
    op[li]      = 0.25f*o0 + bias[li];
    op[16 + li] = 0.25f*o1 + bias[16 + li];
    if (has3) op[32 + li] = 0.25f*o2 + bias[32 + li];
  }
}

// ======================= launch =======================

extern "C" void kernel_launch(void* const* d_in, const int* in_sizes, int n_in,
                              void* d_out, int out_size, void* d_ws, size_t ws_size,
                              hipStream_t stream)
{
  const float* x     = (const float*)d_in[0];
  const int*   ei    = (const int*)  d_in[1];
  const float* Wl1   = (const float*)d_in[2];
  const float* bl1   = (const float*)d_in[3];
  const float* Wr1   = (const float*)d_in[4];
  const float* br1   = (const float*)d_in[5];
  const float* att1  = (const float*)d_in[6];
  const float* bias1 = (const float*)d_in[7];
  const float* Wl2   = (const float*)d_in[8];
  const float* bl2   = (const float*)d_in[9];
  const float* Wr2   = (const float*)d_in[10];
  const float* br2   = (const float*)d_in[11];
  const float* att2  = (const float*)d_in[12];
  const float* bias2 = (const float*)d_in[13];
  float* out = (float*)d_out;

  char* w = (char*)d_ws;
  size_t off = 0;
  auto alloc = [&](size_t bytes) -> void* {
    void* p = w + off;
    off = (off + bytes + 255) & ~(size_t)255;
    return p;
  };

  int* deg    = (int*)alloc((size_t)NNODES*4);
  int* rowptr = (int*)alloc((size_t)NNODES*4);
  int* pos    = (int*)alloc((size_t)NNODES*4);
  int* bsum   = (int*)alloc(256*4);
  int* boff   = (int*)alloc(256*4);
  int* csr    = (int*)alloc((size_t)ET*4);
  float* bufA = (float*)alloc((size_t)NNODES*160*4);   // xl1 then xl2
  float* bufB = (float*)alloc((size_t)NNODES*160*4);   // xr1 then xr2
  float* hbuf = (float*)alloc((size_t)NNODES*128*4);   // layer-1 output h

  const int NB = (NNODES + 255)/256;         // 196
  const int EB = (ET + 255)/256;             // 3321

  hipMemsetAsync(deg, 0, (size_t)NNODES*4, stream);
  k_count<<<EB, 256, 0, stream>>>(ei, deg);
  k_bsum <<<NB, 256, 0, stream>>>(deg, bsum);
  k_scanb<<<1, 256, 0, stream>>>(bsum, NB, boff);
  k_scanw<<<NB, 256, 0, stream>>>(deg, boff, rowptr);
  hipMemcpyAsync(pos, rowptr, (size_t)NNODES*4, hipMemcpyDeviceToDevice, stream);
  k_scatter<<<EB, 256, 0, stream>>>(ei, pos, csr);

  dim3 g1((NNODES + BM - 1)/BM, 256/BN);   // (391, 4)
  k_gemm<<<g1, 256, 0, stream>>>(x, 256, 256, NNODES,
                                 Wl1, Wr1, 128, bl1, br1, 128,
                                 bufA, 128, bufB, 128);
  k_agg1<<<NNODES/4, 256, 0, stream>>>(bufA, bufB, rowptr, deg, csr, att1, bias1, hbuf);

  dim3 g2((NNODES + BM - 1)/BM, 320/BN);   // (391, 5)
  k_gemm<<<g2, 256, 0, stream>>>(hbuf, 128, 128, NNODES,
                                 Wl2, Wr2, 160, bl2, br2, 160,
                                 bufA, 160, bufB, 160);
  k_agg2<<<NNODES/4, 256, 0, stream>>>(bufA, bufB, rowptr, deg, csr, att2, bias2, out);
}

// Round 2
// 491.251 us; speedup vs baseline: 1.2321x; 1.2321x over previous
//
#include <hip/hip_runtime.h>
#include <math.h>

#define NNODES 50000
#define NEDGES 800000
#define ET (NNODES + NEDGES)   // 850000 with self loops
#define SLOPE 0.2f
#define OUTD 40

// ======================= CSR build =======================

__global__ void k_count(const int* __restrict__ ei, int* __restrict__ deg){
  int e = blockIdx.x*256 + threadIdx.x;
  if (e >= ET) return;
  int dst = (e < NEDGES) ? ei[NEDGES + e] : (e - NEDGES);
  atomicAdd(&deg[dst], 1);
}

__global__ void k_bsum(const int* __restrict__ deg, int* __restrict__ bsum){
  int i = blockIdx.x*256 + threadIdx.x;
  int v = (i < NNODES) ? deg[i] : 0;
  for (int o = 1; o < 64; o <<= 1) v += __shfl_xor(v, o);
  __shared__ int ws[4];
  if ((threadIdx.x & 63) == 0) ws[threadIdx.x >> 6] = v;
  __syncthreads();
  if (threadIdx.x == 0) bsum[blockIdx.x] = ws[0] + ws[1] + ws[2] + ws[3];
}

__global__ void k_scanb(const int* __restrict__ bsum, int nb, int* __restrict__ boff){
  __shared__ int sm[256];
  int t = threadIdx.x;
  int v = (t < nb) ? bsum[t] : 0;
  sm[t] = v; __syncthreads();
  for (int d = 1; d < 256; d <<= 1){
    int x = (t >= d) ? sm[t - d] : 0;
    __syncthreads();
    sm[t] += x;
    __syncthreads();
  }
  if (t < nb) boff[t] = sm[t] - v;   // exclusive
}

__global__ void k_scanw(const int* __restrict__ deg, const int* __restrict__ boff,
                        int* __restrict__ rowptr){
  __shared__ int sm[256];
  int t = threadIdx.x, i = blockIdx.x*256 + t;
  int v = (i < NNODES) ? deg[i] : 0;
  sm[t] = v; __syncthreads();
  for (int d = 1; d < 256; d <<= 1){
    int x = (t >= d) ? sm[t - d] : 0;
    __syncthreads();
    sm[t] += x;
    __syncthreads();
  }
  if (i < NNODES) rowptr[i] = boff[blockIdx.x] + sm[t] - v;  // exclusive
}

__global__ void k_scatter(const int* __restrict__ ei, int* __restrict__ pos,
                          int* __restrict__ csr_src){
  int e = blockIdx.x*256 + threadIdx.x;
  if (e >= ET) return;
  int src, dst;
  if (e < NEDGES){ src = ei[e]; dst = ei[NEDGES + e]; }
  else           { src = dst = e - NEDGES; }
  int p = atomicAdd(&pos[dst], 1);
  csr_src[p] = src;
}

// ======================= GEMM (f32, dual-weight fused) =======================
// (unchanged from R1 — ~55 TF; MFMA rewrite is a separate, later change)

#define BM 128
#define BN 64
#define BK 16

__global__ __launch_bounds__(256) void k_gemm(
    const float* __restrict__ X, int ldx, int Kdim, int Nrows,
    const float* __restrict__ W0, const float* __restrict__ W1, int ldw,
    const float* __restrict__ b0, const float* __restrict__ b1, int split,
    float* __restrict__ O0, int ld0, float* __restrict__ O1, int ld1)
{
  __shared__ float As[BK][BM + 4];   // transposed: As[k][row]
  __shared__ float Bs[BK][BN];

  int t  = threadIdx.x;
  int tc = t & 15;
  int tr = t >> 4;
  int row0 = blockIdx.x * BM;
  int col0 = blockIdx.y * BN;

  int arow = t >> 1;
  int akh  = (t & 1) * 8;
  int agr  = min(row0 + arow, Nrows - 1);
  const float* Xp = X + (size_t)agr * ldx + akh;

  int bk  = t >> 4;
  int bc4 = (t & 15) * 4;
  int gcb = col0 + bc4;
  const float* Wp = (gcb < split) ? (W0 + gcb) : (W1 + (gcb - split));

  float acc[8][4];
  #pragma unroll
  for (int i = 0; i < 8; ++i)
    #pragma unroll
    for (int j = 0; j < 4; ++j) acc[i][j] = 0.f;

  for (int k0 = 0; k0 < Kdim; k0 += BK){
    float4 av0 = *(const float4*)(Xp + k0);
    float4 av1 = *(const float4*)(Xp + k0 + 4);
    float4 bv  = *(const float4*)(Wp + (size_t)(k0 + bk) * ldw);
    __syncthreads();
    As[akh+0][arow] = av0.x; As[akh+1][arow] = av0.y;
    As[akh+2][arow] = av0.z; As[akh+3][arow] = av0.w;
    As[akh+4][arow] = av1.x; As[akh+5][arow] = av1.y;
    As[akh+6][arow] = av1.z; As[akh+7][arow] = av1.w;
    *(float4*)&Bs[bk][bc4] = bv;
    __syncthreads();
    #pragma unroll
    for (int kk = 0; kk < BK; ++kk){
      float4 a0 = *(const float4*)&As[kk][tr*8];
      float4 a1 = *(const float4*)&As[kk][tr*8 + 4];
      float4 b  = *(const float4*)&Bs[kk][tc*4];
      float a[8] = {a0.x,a0.y,a0.z,a0.w,a1.x,a1.y,a1.z,a1.w};
      float bb[4] = {b.x,b.y,b.z,b.w};
      #pragma unroll
      for (int i = 0; i < 8; ++i)
        #pragma unroll
        for (int j = 0; j < 4; ++j) acc[i][j] += a[i]*bb[j];
    }
  }

  int gcc = col0 + tc*4;
  const float* bp = (gcc < split) ? (b0 + gcc) : (b1 + (gcc - split));
  float4 bias4 = *(const float4*)bp;
  float* Ob; int ldO, cc;
  if (gcc < split){ Ob = O0; ldO = ld0; cc = gcc; }
  else            { Ob = O1; ldO = ld1; cc = gcc - split; }
  #pragma unroll
  for (int i = 0; i < 8; ++i){
    int gr = row0 + tr*8 + i;
    if (gr < Nrows){
      float4 v = make_float4(acc[i][0] + bias4.x, acc[i][1] + bias4.y,
                             acc[i][2] + bias4.z, acc[i][3] + bias4.w);
      *(float4*)(Ob + (size_t)gr * ldO + cc) = v;
    }
  }
}

// ======================= Layer 1 aggregation (fused softmax) =================
// 32 lanes per node (2 nodes/wave, 8 nodes/block). Lane (h,li): h=l>>3, li=l&7
// owns channels h*32 + 4*li .. +3 as one float4. Logit reduce = 3 shfl over
// the 8-lane head group. Edge loop software-pipelined: row prefetch 1-ahead,
// csr index prefetch 2-ahead.
__global__ __launch_bounds__(256) void k_agg1(
    const float* __restrict__ xl, const float* __restrict__ xr,
    const int* __restrict__ rowptr, const int* __restrict__ deg,
    const int* __restrict__ csr, const float* __restrict__ att,
    const float* __restrict__ bias, float* __restrict__ hout)
{
  int node = blockIdx.x*8 + (threadIdx.x >> 5);
  int l  = threadIdx.x & 31;
  int h  = l >> 3;
  int li = l & 7;
  int c0 = h*32 + li*4;

  float4 av  = *(const float4*)(att + c0);
  float4 xrv = *(const float4*)(xr + (size_t)node*128 + c0);

  int start = rowptr[node], cnt = deg[node];

  // prologue: prefetch edge 0 row and edge 1 index (cnt >= 1 always: self loop)
  int sp = csr[start];
  float4 vn = *(const float4*)(xl + (size_t)sp*128 + c0);
  int sn = (cnt > 1) ? csr[start + 1] : sp;

  float m = -INFINITY, s = 0.f;
  float4 acc = make_float4(0.f, 0.f, 0.f, 0.f);

  for (int i = 0; i < cnt; ++i){
    float4 v = vn;
    int scur = sn;
    // prefetch row i+1 and index i+2
    vn = *(const float4*)(xl + (size_t)scur*128 + c0);
    int i2 = i + 2;
    sn = csr[start + ((i2 < cnt) ? i2 : (cnt - 1))];

    float g0 = v.x + xrv.x; g0 = g0 > 0.f ? g0 : SLOPE*g0;
    float g1 = v.y + xrv.y; g1 = g1 > 0.f ? g1 : SLOPE*g1;
    float g2 = v.z + xrv.z; g2 = g2 > 0.f ? g2 : SLOPE*g2;
    float g3 = v.w + xrv.w; g3 = g3 > 0.f ? g3 : SLOPE*g3;
    float p = g0*av.x + g1*av.y + g2*av.z + g3*av.w;
    p += __shfl_xor(p, 1); p += __shfl_xor(p, 2); p += __shfl_xor(p, 4);

    float mn  = fmaxf(m, p);
    float wgt = __expf(p - mn);
    float sc  = __expf(m - mn);
    s = s*sc + wgt;
    acc.x = acc.x*sc + wgt*v.x;
    acc.y = acc.y*sc + wgt*v.y;
    acc.z = acc.z*sc + wgt*v.z;
    acc.w = acc.w*sc + wgt*v.w;
    m = mn;
  }

  float inv = 1.f/(s + 1e-16f);
  float4 b4 = *(const float4*)(bias + c0);
  float o0 = acc.x*inv + b4.x;
  float o1 = acc.y*inv + b4.y;
  float o2 = acc.z*inv + b4.z;
  float o3 = acc.w*inv + b4.w;
  o0 = o0 > 0.f ? o0 : (__expf(o0) - 1.f);
  o1 = o1 > 0.f ? o1 : (__expf(o1) - 1.f);
  o2 = o2 > 0.f ? o2 : (__expf(o2) - 1.f);
  o3 = o3 > 0.f ? o3 : (__expf(o3) - 1.f);
  *(float4*)(hout + (size_t)node*128 + c0) = make_float4(o0, o1, o2, o3);
}

// ======================= Layer 2 aggregation (head-mean) =====================
// One wave per node. Lane (h,li): h=l>>4, li=l&15; lanes with li<10 own
// channels h*40 + 4*li .. +3 (float4); li>=10 idle (contribute zeros).
// Logit reduce = 4 shfl over 16-lane head group; head-mean = 2 shfl.
__global__ __launch_bounds__(256) void k_agg2(
    const float* __restrict__ xl, const float* __restrict__ xr,
    const int* __restrict__ rowptr, const int* __restrict__ deg,
    const int* __restrict__ csr, const float* __restrict__ att,
    const float* __restrict__ bias, float* __restrict__ out)
{
  int node = blockIdx.x*4 + (threadIdx.x >> 6);
  int l  = threadIdx.x & 63;
  int h  = l >> 4;
  int li = l & 15;
  bool act = (li < 10);
  int c0 = h*40 + li*4;   // only meaningful when act

  float4 av  = make_float4(0.f,0.f,0.f,0.f);
  float4 xrv = make_float4(0.f,0.f,0.f,0.f);
  if (act){
    av  = *(const float4*)(att + c0);
    xrv = *(const float4*)(xr + (size_t)node*160 + c0);
  }

  int start = rowptr[node], cnt = deg[node];

  int sp = csr[start];
  float4 vn = make_float4(0.f,0.f,0.f,0.f);
  if (act) vn = *(const float4*)(xl + (size_t)sp*160 + c0);
  int sn = (cnt > 1) ? csr[start + 1] : sp;

  float m = -INFINITY, s = 0.f;
  float4 acc = make_float4(0.f,0.f,0.f,0.f);

  for (int i = 0; i < cnt; ++i){
    float4 v = vn;
    int scur = sn;
    if (act) vn = *(const float4*)(xl + (size_t)scur*160 + c0);
    int i2 = i + 2;
    sn = csr[start + ((i2 < cnt) ? i2 : (cnt - 1))];

    float g0 = v.x + xrv.x; g0 = g0 > 0.f ? g0 : SLOPE*g0;
    float g1 = v.y + xrv.y; g1 = g1 > 0.f ? g1 : SLOPE*g1;
    float g2 = v.z + xrv.z; g2 = g2 > 0.f ? g2 : SLOPE*g2;
    float g3 = v.w + xrv.w; g3 = g3 > 0.f ? g3 : SLOPE*g3;
    float p = g0*av.x + g1*av.y + g2*av.z + g3*av.w;  // zeros on idle lanes
    p += __shfl_xor(p, 1); p += __shfl_xor(p, 2);
    p += __shfl_xor(p, 4); p += __shfl_xor(p, 8);

    float mn  = fmaxf(m, p);
    float wgt = __expf(p - mn);
    float sc  = __expf(m - mn);
    s = s*sc + wgt;
    acc.x = acc.x*sc + wgt*v.x;
    acc.y = acc.y*sc + wgt*v.y;
    acc.z = acc.z*sc + wgt*v.z;
    acc.w = acc.w*sc + wgt*v.w;
    m = mn;
  }

  float inv = 1.f/(s + 1e-16f);
  float o0 = acc.x*inv, o1 = acc.y*inv, o2 = acc.z*inv, o3 = acc.w*inv;
  // head mean: sum across the 4 head groups (lanes l, l^16, l^32, l^48)
  o0 += __shfl_xor(o0, 16); o0 += __shfl_xor(o0, 32);
  o1 += __shfl_xor(o1, 16); o1 += __shfl_xor(o1, 32);
  o2 += __shfl_xor(o2, 16); o2 += __shfl_xor(o2, 32);
  o3 += __shfl_xor(o3, 16); o3 += __shfl_xor(o3, 32);
  if (h == 0 && act){
    float4 b4 = *(const float4*)(bias + li*4);
    float4 r = make_float4(0.25f*o0 + b4.x, 0.25f*o1 + b4.y,
                           0.25f*o2 + b4.z, 0.25f*o3 + b4.w);
    *(float4*)(out + (size_t)node*OUTD + li*4) = r;
  }
}

// ======================= launch =======================

extern "C" void kernel_launch(void* const* d_in, const int* in_sizes, int n_in,
                              void* d_out, int out_size, void* d_ws, size_t ws_size,
                              hipStream_t stream)
{
  const float* x     = (const float*)d_in[0];
  const int*   ei    = (const int*)  d_in[1];
  const float* Wl1   = (const float*)d_in[2];
  const float* bl1   = (const float*)d_in[3];
  const float* Wr1   = (const float*)d_in[4];
  const float* br1   = (const float*)d_in[5];
  const float* att1  = (const float*)d_in[6];
  const float* bias1 = (const float*)d_in[7];
  const float* Wl2   = (const float*)d_in[8];
  const float* bl2   = (const float*)d_in[9];
  const float* Wr2   = (const float*)d_in[10];
  const float* br2   = (const float*)d_in[11];
  const float* att2  = (const float*)d_in[12];
  const float* bias2 = (const float*)d_in[13];
  float* out = (float*)d_out;

  char* w = (char*)d_ws;
  size_t off = 0;
  auto alloc = [&](size_t bytes) -> void* {
    void* p = w + off;
    off = (off + bytes + 255) & ~(size_t)255;
    return p;
  };

  int* deg    = (int*)alloc((size_t)NNODES*4);
  int* rowptr = (int*)alloc((size_t)NNODES*4);
  int* pos    = (int*)alloc((size_t)NNODES*4);
  int* bsum   = (int*)alloc(256*4);
  int* boff   = (int*)alloc(256*4);
  int* csr    = (int*)alloc((size_t)ET*4);
  float* bufA = (float*)alloc((size_t)NNODES*160*4);   // xl1 then xl2
  float* bufB = (float*)alloc((size_t)NNODES*160*4);   // xr1 then xr2
  float* hbuf = (float*)alloc((size_t)NNODES*128*4);   // layer-1 output h

  const int NB = (NNODES + 255)/256;         // 196
  const int EB = (ET + 255)/256;             // 3321

  hipMemsetAsync(deg, 0, (size_t)NNODES*4, stream);
  k_count<<<EB, 256, 0, stream>>>(ei, deg);
  k_bsum <<<NB, 256, 0, stream>>>(deg, bsum);
  k_scanb<<<1, 256, 0, stream>>>(bsum, NB, boff);
  k_scanw<<<NB, 256, 0, stream>>>(deg, boff, rowptr);
  hipMemcpyAsync(pos, rowptr, (size_t)NNODES*4, hipMemcpyDeviceToDevice, stream);
  k_scatter<<<EB, 256, 0, stream>>>(ei, pos, csr);

  dim3 g1((NNODES + BM - 1)/BM, 256/BN);   // (391, 4)
  k_gemm<<<g1, 256, 0, stream>>>(x, 256, 256, NNODES,
                                 Wl1, Wr1, 128, bl1, br1, 128,
                                 bufA, 128, bufB, 128);
  k_agg1<<<6250, 256, 0, stream>>>(bufA, bufB, rowptr, deg, csr, att1, bias1, hbuf);

  dim3 g2((NNODES + BM - 1)/BM, 320/BN);   // (391, 5)
  k_gemm<<<g2, 256, 0, stream>>>(hbuf, 128, 128, NNODES,
                                 Wl2, Wr2, 160, bl2, br2, 160,
                                 bufA, 160, bufB, 160);
  k_agg2<<<NNODES/4, 256, 0, stream>>>(bufA, bufB, rowptr, deg, csr, att2, bias2, out);
}

// Round 4
// 451.766 us; speedup vs baseline: 1.3398x; 1.0874x over previous
//
#include <hip/hip_runtime.h>
#include <math.h>

#define NNODES 50000
#define NEDGES 800000
#define ET (NNODES + NEDGES)   // 850000 with self loops
#define SLOPE 0.2f
#define OUTD 40

typedef __attribute__((ext_vector_type(8))) short short8;
typedef __attribute__((ext_vector_type(4))) float f32x4;

// float -> bf16 bits, round-to-nearest-even
__device__ inline unsigned short f2bf(float f){
  unsigned u = __float_as_uint(f);
  unsigned r = (u + 0x7FFFu + ((u >> 16) & 1u)) >> 16;
  return (unsigned short)r;
}
__device__ inline float bf2f(unsigned short h){
  return __uint_as_float(((unsigned)h) << 16);
}

// ======================= CSR build =======================

__global__ void k_count(const int* __restrict__ ei, int* __restrict__ deg){
  int e = blockIdx.x*256 + threadIdx.x;
  if (e >= ET) return;
  int dst = (e < NEDGES) ? ei[NEDGES + e] : (e - NEDGES);
  atomicAdd(&deg[dst], 1);
}

__global__ void k_bsum(const int* __restrict__ deg, int* __restrict__ bsum){
  int i = blockIdx.x*256 + threadIdx.x;
  int v = (i < NNODES) ? deg[i] : 0;
  for (int o = 1; o < 64; o <<= 1) v += __shfl_xor(v, o);
  __shared__ int ws[4];
  if ((threadIdx.x & 63) == 0) ws[threadIdx.x >> 6] = v;
  __syncthreads();
  if (threadIdx.x == 0) bsum[blockIdx.x] = ws[0] + ws[1] + ws[2] + ws[3];
}

__global__ void k_scanb(const int* __restrict__ bsum, int nb, int* __restrict__ boff){
  __shared__ int sm[256];
  int t = threadIdx.x;
  int v = (t < nb) ? bsum[t] : 0;
  sm[t] = v; __syncthreads();
  for (int d = 1; d < 256; d <<= 1){
    int x = (t >= d) ? sm[t - d] : 0;
    __syncthreads();
    sm[t] += x;
    __syncthreads();
  }
  if (t < nb) boff[t] = sm[t] - v;   // exclusive
}

__global__ void k_scanw(const int* __restrict__ deg, const int* __restrict__ boff,
                        int* __restrict__ rowptr){
  __shared__ int sm[256];
  int t = threadIdx.x, i = blockIdx.x*256 + t;
  int v = (i < NNODES) ? deg[i] : 0;
  sm[t] = v; __syncthreads();
  for (int d = 1; d < 256; d <<= 1){
    int x = (t >= d) ? sm[t - d] : 0;
    __syncthreads();
    sm[t] += x;
    __syncthreads();
  }
  if (i < NNODES) rowptr[i] = boff[blockIdx.x] + sm[t] - v;  // exclusive
}

__global__ void k_scatter(const int* __restrict__ ei, int* __restrict__ pos,
                          int* __restrict__ csr_src){
  int e = blockIdx.x*256 + threadIdx.x;
  if (e >= ET) return;
  int src, dst;
  if (e < NEDGES){ src = ei[e]; dst = ei[NEDGES + e]; }
  else           { src = dst = e - NEDGES; }
  int p = atomicAdd(&pos[dst], 1);
  csr_src[p] = src;
}

// ======================= split kernels (f32 -> bf16 hi/lo) ===================

// X [rows][K] f32 -> Xh, Xl [rows][K] bf16. One thread = 8 elements.
__global__ void k_split_x(const float* __restrict__ x,
                          unsigned short* __restrict__ xh,
                          unsigned short* __restrict__ xl, int total8){
  int idx = blockIdx.x*256 + threadIdx.x;
  if (idx >= total8) return;
  const float4* p = (const float4*)x + (size_t)idx*2;
  float4 f0 = p[0], f1 = p[1];
  float f[8] = {f0.x,f0.y,f0.z,f0.w,f1.x,f1.y,f1.z,f1.w};
  unsigned h[8], lo[8];
  #pragma unroll
  for (int j = 0; j < 8; ++j){
    h[j] = f2bf(f[j]);
    lo[j] = f2bf(f[j] - bf2f((unsigned short)h[j]));
  }
  uint4 hv = make_uint4(h[0]|(h[1]<<16), h[2]|(h[3]<<16), h[4]|(h[5]<<16), h[6]|(h[7]<<16));
  uint4 lv = make_uint4(lo[0]|(lo[1]<<16), lo[2]|(lo[3]<<16), lo[4]|(lo[5]<<16), lo[6]|(lo[7]<<16));
  *(uint4*)(xh + (size_t)idx*8) = hv;
  *(uint4*)(xl + (size_t)idx*8) = lv;
}

// Fused W^T split: th/tl [Nf][K] bf16 where col n<split comes from W0[k][n]
// (row-stride split), else W1[k][n-split] (row-stride Nf-split).
__global__ void k_split_wt(const float* __restrict__ W0, const float* __restrict__ W1,
                           int split, int K, int Nf,
                           unsigned short* __restrict__ th,
                           unsigned short* __restrict__ tl){
  int kg8 = K >> 3;
  int idx = blockIdx.x*256 + threadIdx.x;
  if (idx >= Nf*kg8) return;
  int n  = idx / kg8;
  int kg = (idx - n*kg8) * 8;
  const float* src; int ld;
  if (n < split){ src = W0 + n;          ld = split; }
  else          { src = W1 + (n - split); ld = Nf - split; }
  unsigned h[8], lo[8];
  #pragma unroll
  for (int j = 0; j < 8; ++j){
    float v = src[(size_t)(kg + j) * ld];
    h[j]  = f2bf(v);
    lo[j] = f2bf(v - bf2f((unsigned short)h[j]));
  }
  uint4 hv = make_uint4(h[0]|(h[1]<<16), h[2]|(h[3]<<16), h[4]|(h[5]<<16), h[6]|(h[7]<<16));
  uint4 lv = make_uint4(lo[0]|(lo[1]<<16), lo[2]|(lo[3]<<16), lo[4]|(lo[5]<<16), lo[6]|(lo[7]<<16));
  *(uint4*)(th + (size_t)n*K + kg) = hv;
  *(uint4*)(tl + (size_t)n*K + kg) = lv;
}

// ======================= MFMA GEMM (split-bf16 x3) ==========================
// O[row][col] = sum_k X[row][k]*W^T[col][k] + bias(col), f32-accurate via
// hi*hi + hi*lo + lo*hi. Block tile 128x128, 4 waves (2x2), wave tile 64x64
// = 4x4 frags of 16x16, K-step 32 (mfma_f32_16x16x32_bf16).
// LDS row layout: [r][64] bf16 = hi k0..31 | lo k0..31, XOR-swizzled
// (byte ^= (r&7)<<4) with pre-swizzled global source for global_load_lds.

__global__ __launch_bounds__(256) void k_gemm_mfma(
    const unsigned short* __restrict__ Xh, const unsigned short* __restrict__ Xl,
    int Kd, int M,
    const unsigned short* __restrict__ Wth, const unsigned short* __restrict__ Wtl,
    int Nf, int split,
    const float* __restrict__ b0, const float* __restrict__ b1,
    float* __restrict__ O0, float* __restrict__ O1, int ldO)
{
  __shared__ unsigned short ldsA[128*64];
  __shared__ unsigned short ldsB[128*64];
  char* cA = (char*)ldsA;
  char* cB = (char*)ldsB;

  int t = threadIdx.x;
  int w = t >> 6, l = t & 63;
  int wr = w >> 1, wc = w & 1;
  int lr = l & 15, lg = l >> 4;

  int row0 = blockIdx.x * 128;
  int col0 = blockIdx.y * 128;

  f32x4 acc[4][4];
  #pragma unroll
  for (int i = 0; i < 4; ++i)
    #pragma unroll
    for (int j = 0; j < 4; ++j) acc[i][j] = (f32x4){0.f,0.f,0.f,0.f};

  // per-thread staging geometry (same for A and B regions)
  int sr_off = l >> 3;          // row within chunk
  int slot   = 0;               // computed per chunk below

  for (int k0 = 0; k0 < Kd; k0 += 32){
    __syncthreads();   // previous compute done reading LDS
    // ---- stage A (16KB) and B (16KB): 4 chunks each per wave ----
    #pragma unroll
    for (int i = 0; i < 4; ++i){
      int chunk = w*4 + i;
      int r = chunk*8 + sr_off;
      slot = (l & 7) ^ (r & 7);
      int h = slot >> 2, g = slot & 3;
      int row = row0 + r; if (row > M-1) row = M-1;
      const unsigned short* src = (h ? Xl : Xh) + (size_t)row*Kd + k0 + g*8;
      __builtin_amdgcn_global_load_lds(
          (const __attribute__((address_space(1))) void*)src,
          (__attribute__((address_space(3))) void*)(cA + chunk*1024), 16, 0, 0);
    }
    #pragma unroll
    for (int i = 0; i < 4; ++i){
      int chunk = w*4 + i;
      int r = chunk*8 + sr_off;
      slot = (l & 7) ^ (r & 7);
      int h = slot >> 2, g = slot & 3;
      int n = col0 + r; if (n > Nf-1) n = Nf-1;
      const unsigned short* src = (h ? Wtl : Wth) + (size_t)n*Kd + k0 + g*8;
      __builtin_amdgcn_global_load_lds(
          (const __attribute__((address_space(1))) void*)src,
          (__attribute__((address_space(3))) void*)(cB + chunk*1024), 16, 0, 0);
    }
    __syncthreads();   // compiler drains vmcnt(0) before barrier

    // ---- fragments ----
    short8 ah[4], al[4], bh[4], bl[4];
    #pragma unroll
    for (int mi = 0; mi < 4; ++mi){
      int r = wr*64 + mi*16 + lr;
      unsigned sw = (unsigned)((r & 7) << 4);
      unsigned ba = (unsigned)(r*128 + lg*16);
      ah[mi] = *(const short8*)(cA + (ba ^ sw));
      al[mi] = *(const short8*)(cA + ((ba + 64) ^ sw));
    }
    #pragma unroll
    for (int ni = 0; ni < 4; ++ni){
      int n = wc*64 + ni*16 + lr;
      unsigned sw = (unsigned)((n & 7) << 4);
      unsigned bb = (unsigned)(n*128 + lg*16);
      bh[ni] = *(const short8*)(cB + (bb ^ sw));
      bl[ni] = *(const short8*)(cB + ((bb + 64) ^ sw));
    }
    // ---- 48 MFMA ----
    #pragma unroll
    for (int mi = 0; mi < 4; ++mi)
      #pragma unroll
      for (int ni = 0; ni < 4; ++ni){
        acc[mi][ni] = __builtin_amdgcn_mfma_f32_16x16x32_bf16(ah[mi], bh[ni], acc[mi][ni], 0, 0, 0);
        acc[mi][ni] = __builtin_amdgcn_mfma_f32_16x16x32_bf16(ah[mi], bl[ni], acc[mi][ni], 0, 0, 0);
        acc[mi][ni] = __builtin_amdgcn_mfma_f32_16x16x32_bf16(al[mi], bh[ni], acc[mi][ni], 0, 0, 0);
      }
  }

  // ---- epilogue: bias + split store (C/D: col=lane&15, row=(lane>>4)*4+q) ----
  #pragma unroll
  for (int ni = 0; ni < 4; ++ni){
    int col = col0 + wc*64 + ni*16 + lr;
    if (col >= Nf) continue;
    float bias; float* O;
    if (col < split){ bias = b0[col];         O = O0 + col; }
    else            { bias = b1[col - split]; O = O1 + (col - split); }
    #pragma unroll
    for (int mi = 0; mi < 4; ++mi){
      int rbase = row0 + wr*64 + mi*16 + lg*4;
      #pragma unroll
      for (int q = 0; q < 4; ++q){
        int row = rbase + q;
        if (row < M) O[(size_t)row * ldO] = acc[mi][ni][q] + bias;
      }
    }
  }
}

// ======================= Layer 1 aggregation (fused softmax) =================
// 32 lanes per node. Writes h split to bf16 hi/lo (layer-2 GEMM input).
__global__ __launch_bounds__(256) void k_agg1(
    const float* __restrict__ xl, const float* __restrict__ xr,
    const int* __restrict__ rowptr, const int* __restrict__ deg,
    const int* __restrict__ csr, const float* __restrict__ att,
    const float* __restrict__ bias,
    unsigned short* __restrict__ Hh, unsigned short* __restrict__ Hl)
{
  int node = blockIdx.x*8 + (threadIdx.x >> 5);
  int l  = threadIdx.x & 31;
  int h  = l >> 3;
  int li = l & 7;
  int c0 = h*32 + li*4;

  float4 av  = *(const float4*)(att + c0);
  float4 xrv = *(const float4*)(xr + (size_t)node*128 + c0);

  int start = rowptr[node], cnt = deg[node];

  int sp = csr[start];
  float4 vn = *(const float4*)(xl + (size_t)sp*128 + c0);
  int sn = (cnt > 1) ? csr[start + 1] : sp;

  float m = -INFINITY, s = 0.f;
  float4 acc = make_float4(0.f, 0.f, 0.f, 0.f);

  for (int i = 0; i < cnt; ++i){
    float4 v = vn;
    int scur = sn;
    vn = *(const float4*)(xl + (size_t)scur*128 + c0);
    int i2 = i + 2;
    sn = csr[start + ((i2 < cnt) ? i2 : (cnt - 1))];

    float g0 = v.x + xrv.x; g0 = g0 > 0.f ? g0 : SLOPE*g0;
    float g1 = v.y + xrv.y; g1 = g1 > 0.f ? g1 : SLOPE*g1;
    float g2 = v.z + xrv.z; g2 = g2 > 0.f ? g2 : SLOPE*g2;
    float g3 = v.w + xrv.w; g3 = g3 > 0.f ? g3 : SLOPE*g3;
    float p = g0*av.x + g1*av.y + g2*av.z + g3*av.w;
    p += __shfl_xor(p, 1); p += __shfl_xor(p, 2); p += __shfl_xor(p, 4);

    float mn  = fmaxf(m, p);
    float wgt = __expf(p - mn);
    float sc  = __expf(m - mn);
    s = s*sc + wgt;
    acc.x = acc.x*sc + wgt*v.x;
    acc.y = acc.y*sc + wgt*v.y;
    acc.z = acc.z*sc + wgt*v.z;
    acc.w = acc.w*sc + wgt*v.w;
    m = mn;
  }

  float inv = 1.f/(s + 1e-16f);
  float4 b4 = *(const float4*)(bias + c0);
  float o[4];
  o[0] = acc.x*inv + b4.x;
  o[1] = acc.y*inv + b4.y;
  o[2] = acc.z*inv + b4.z;
  o[3] = acc.w*inv + b4.w;
  unsigned hh[4], hl[4];
  #pragma unroll
  for (int j = 0; j < 4; ++j){
    float e = o[j] > 0.f ? o[j] : (__expf(o[j]) - 1.f);   // ELU
    hh[j] = f2bf(e);
    hl[j] = f2bf(e - bf2f((unsigned short)hh[j]));
  }
  *(uint2*)(Hh + (size_t)node*128 + c0) = make_uint2(hh[0]|(hh[1]<<16), hh[2]|(hh[3]<<16));
  *(uint2*)(Hl + (size_t)node*128 + c0) = make_uint2(hl[0]|(hl[1]<<16), hl[2]|(hl[3]<<16));
}

// ======================= Layer 2 aggregation (head-mean) =====================
__global__ __launch_bounds__(256) void k_agg2(
    const float* __restrict__ xl, const float* __restrict__ xr,
    const int* __restrict__ rowptr, const int* __restrict__ deg,
    const int* __restrict__ csr, const float* __restrict__ att,
    const float* __restrict__ bias, float* __restrict__ out)
{
  int node = blockIdx.x*4 + (threadIdx.x >> 6);
  int l  = threadIdx.x & 63;
  int h  = l >> 4;
  int li = l & 15;
  bool act = (li < 10);
  int c0 = h*40 + li*4;

  float4 av  = make_float4(0.f,0.f,0.f,0.f);
  float4 xrv = make_float4(0.f,0.f,0.f,0.f);
  if (act){
    av  = *(const float4*)(att + c0);
    xrv = *(const float4*)(xr + (size_t)node*160 + c0);
  }

  int start = rowptr[node], cnt = deg[node];

  int sp = csr[start];
  float4 vn = make_float4(0.f,0.f,0.f,0.f);
  if (act) vn = *(const float4*)(xl + (size_t)sp*160 + c0);
  int sn = (cnt > 1) ? csr[start + 1] : sp;

  float m = -INFINITY, s = 0.f;
  float4 acc = make_float4(0.f,0.f,0.f,0.f);

  for (int i = 0; i < cnt; ++i){
    float4 v = vn;
    int scur = sn;
    if (act) vn = *(const float4*)(xl + (size_t)scur*160 + c0);
    int i2 = i + 2;
    sn = csr[start + ((i2 < cnt) ? i2 : (cnt - 1))];

    float g0 = v.x + xrv.x; g0 = g0 > 0.f ? g0 : SLOPE*g0;
    float g1 = v.y + xrv.y; g1 = g1 > 0.f ? g1 : SLOPE*g1;
    float g2 = v.z + xrv.z; g2 = g2 > 0.f ? g2 : SLOPE*g2;
    float g3 = v.w + xrv.w; g3 = g3 > 0.f ? g3 : SLOPE*g3;
    float p = g0*av.x + g1*av.y + g2*av.z + g3*av.w;
    p += __shfl_xor(p, 1); p += __shfl_xor(p, 2);
    p += __shfl_xor(p, 4); p += __shfl_xor(p, 8);

    float mn  = fmaxf(m, p);
    float wgt = __expf(p - mn);
    float sc  = __expf(m - mn);
    s = s*sc + wgt;
    acc.x = acc.x*sc + wgt*v.x;
    acc.y = acc.y*sc + wgt*v.y;
    acc.z = acc.z*sc + wgt*v.z;
    acc.w = acc.w*sc + wgt*v.w;
    m = mn;
  }

  float inv = 1.f/(s + 1e-16f);
  float o0 = acc.x*inv, o1 = acc.y*inv, o2 = acc.z*inv, o3 = acc.w*inv;
  o0 += __shfl_xor(o0, 16); o0 += __shfl_xor(o0, 32);
  o1 += __shfl_xor(o1, 16); o1 += __shfl_xor(o1, 32);
  o2 += __shfl_xor(o2, 16); o2 += __shfl_xor(o2, 32);
  o3 += __shfl_xor(o3, 16); o3 += __shfl_xor(o3, 32);
  if (h == 0 && act){
    float4 b4 = *(const float4*)(bias + li*4);
    float4 r = make_float4(0.25f*o0 + b4.x, 0.25f*o1 + b4.y,
                           0.25f*o2 + b4.z, 0.25f*o3 + b4.w);
    *(float4*)(out + (size_t)node*OUTD + li*4) = r;
  }
}

// ======================= launch =======================

extern "C" void kernel_launch(void* const* d_in, const int* in_sizes, int n_in,
                              void* d_out, int out_size, void* d_ws, size_t ws_size,
                              hipStream_t stream)
{
  const float* x     = (const float*)d_in[0];
  const int*   ei    = (const int*)  d_in[1];
  const float* Wl1   = (const float*)d_in[2];
  const float* bl1   = (const float*)d_in[3];
  const float* Wr1   = (const float*)d_in[4];
  const float* br1   = (const float*)d_in[5];
  const float* att1  = (const float*)d_in[6];
  const float* bias1 = (const float*)d_in[7];
  const float* Wl2   = (const float*)d_in[8];
  const float* bl2   = (const float*)d_in[9];
  const float* Wr2   = (const float*)d_in[10];
  const float* br2   = (const float*)d_in[11];
  const float* att2  = (const float*)d_in[12];
  const float* bias2 = (const float*)d_in[13];
  float* out = (float*)d_out;

  char* w = (char*)d_ws;
  size_t off = 0;
  auto alloc = [&](size_t bytes) -> void* {
    void* p = w + off;
    off = (off + bytes + 255) & ~(size_t)255;
    return p;
  };

  int* deg    = (int*)alloc((size_t)NNODES*4);
  int* rowptr = (int*)alloc((size_t)NNODES*4);
  int* pos    = (int*)alloc((size_t)NNODES*4);
  int* bsum   = (int*)alloc(256*4);
  int* boff   = (int*)alloc(256*4);
  int* csr    = (int*)alloc((size_t)ET*4);
  float* slabA = (float*)alloc((size_t)NNODES*160*4);  // xl1 then xl2
  float* slabB = (float*)alloc((size_t)NNODES*160*4);  // xr1 then xr2
  unsigned short* Xh = (unsigned short*)alloc((size_t)NNODES*256*2);  // later Hh
  unsigned short* Xl = (unsigned short*)alloc((size_t)NNODES*256*2);  // later Hl
  unsigned short* W1th = (unsigned short*)alloc((size_t)256*256*2);
  unsigned short* W1tl = (unsigned short*)alloc((size_t)256*256*2);
  unsigned short* W2th = (unsigned short*)alloc((size_t)320*128*2);
  unsigned short* W2tl = (unsigned short*)alloc((size_t)320*128*2);
  unsigned short* Hh = Xh;   // reuse: X splits dead after gemm1
  unsigned short* Hl = Xl;

  const int NB = (NNODES + 255)/256;         // 196
  const int EB = (ET + 255)/256;             // 3321

  // CSR
  hipMemsetAsync(deg, 0, (size_t)NNODES*4, stream);
  k_count<<<EB, 256, 0, stream>>>(ei, deg);
  k_bsum <<<NB, 256, 0, stream>>>(deg, bsum);
  k_scanb<<<1, 256, 0, stream>>>(bsum, NB, boff);
  k_scanw<<<NB, 256, 0, stream>>>(deg, boff, rowptr);
  hipMemcpyAsync(pos, rowptr, (size_t)NNODES*4, hipMemcpyDeviceToDevice, stream);
  k_scatter<<<EB, 256, 0, stream>>>(ei, pos, csr);

  // splits
  k_split_x<<<(NNODES*256/8 + 255)/256, 256, 0, stream>>>(x, Xh, Xl, NNODES*256/8);
  k_split_wt<<<(256*32 + 255)/256, 256, 0, stream>>>(Wl1, Wr1, 128, 256, 256, W1th, W1tl);
  k_split_wt<<<(320*16 + 255)/256, 256, 0, stream>>>(Wl2, Wr2, 160, 128, 320, W2th, W2tl);

  // layer 1
  dim3 g1((NNODES + 127)/128, 2);   // N=256
  k_gemm_mfma<<<g1, 256, 0, stream>>>(Xh, Xl, 256, NNODES,
                                      W1th, W1tl, 256, 128,
                                      bl1, br1, slabA, slabB, 128);
  k_agg1<<<6250, 256, 0, stream>>>(slabA, slabB, rowptr, deg, csr, att1, bias1, Hh, Hl);

  // layer 2
  dim3 g2((NNODES + 127)/128, 3);   // N=320 (last block half-masked)
  k_gemm_mfma<<<g2, 256, 0, stream>>>(Hh, Hl, 128, NNODES,
                                      W2th, W2tl, 320, 160,
                                      bl2, br2, slabA, slabB, 160);
  k_agg2<<<NNODES/4, 256, 0, stream>>>(slabA, slabB, rowptr, deg, csr, att2, bias2, out);
}

// Round 5
// 449.730 us; speedup vs baseline: 1.3458x; 1.0045x over previous
//
#include <hip/hip_runtime.h>
#include <math.h>

#define NNODES 50000
#define NEDGES 800000
#define ET (NNODES + NEDGES)   // 850000 with self loops
#define SLOPE 0.2f
#define OUTD 40

typedef __attribute__((ext_vector_type(8))) short short8;
typedef __attribute__((ext_vector_type(4))) float f32x4;

// float -> bf16 bits, round-to-nearest-even
__device__ inline unsigned short f2bf(float f){
  unsigned u = __float_as_uint(f);
  unsigned r = (u + 0x7FFFu + ((u >> 16) & 1u)) >> 16;
  return (unsigned short)r;
}
__device__ inline float bf2f(unsigned short h){
  return __uint_as_float(((unsigned)h) << 16);
}

// ======================= CSR build =======================

__global__ void k_count(const int* __restrict__ ei, int* __restrict__ deg){
  int e = blockIdx.x*256 + threadIdx.x;
  if (e >= ET) return;
  int dst = (e < NEDGES) ? ei[NEDGES + e] : (e - NEDGES);
  atomicAdd(&deg[dst], 1);
}

__global__ void k_bsum(const int* __restrict__ deg, int* __restrict__ bsum){
  int i = blockIdx.x*256 + threadIdx.x;
  int v = (i < NNODES) ? deg[i] : 0;
  for (int o = 1; o < 64; o <<= 1) v += __shfl_xor(v, o);
  __shared__ int ws[4];
  if ((threadIdx.x & 63) == 0) ws[threadIdx.x >> 6] = v;
  __syncthreads();
  if (threadIdx.x == 0) bsum[blockIdx.x] = ws[0] + ws[1] + ws[2] + ws[3];
}

__global__ void k_scanb(const int* __restrict__ bsum, int nb, int* __restrict__ boff){
  __shared__ int sm[256];
  int t = threadIdx.x;
  int v = (t < nb) ? bsum[t] : 0;
  sm[t] = v; __syncthreads();
  for (int d = 1; d < 256; d <<= 1){
    int x = (t >= d) ? sm[t - d] : 0;
    __syncthreads();
    sm[t] += x;
    __syncthreads();
  }
  if (t < nb) boff[t] = sm[t] - v;   // exclusive
}

__global__ void k_scanw(const int* __restrict__ deg, const int* __restrict__ boff,
                        int* __restrict__ rowptr){
  __shared__ int sm[256];
  int t = threadIdx.x, i = blockIdx.x*256 + t;
  int v = (i < NNODES) ? deg[i] : 0;
  sm[t] = v; __syncthreads();
  for (int d = 1; d < 256; d <<= 1){
    int x = (t >= d) ? sm[t - d] : 0;
    __syncthreads();
    sm[t] += x;
    __syncthreads();
  }
  if (i < NNODES) rowptr[i] = boff[blockIdx.x] + sm[t] - v;  // exclusive
}

__global__ void k_scatter(const int* __restrict__ ei, int* __restrict__ pos,
                          int* __restrict__ csr_src){
  int e = blockIdx.x*256 + threadIdx.x;
  if (e >= ET) return;
  int src, dst;
  if (e < NEDGES){ src = ei[e]; dst = ei[NEDGES + e]; }
  else           { src = dst = e - NEDGES; }
  int p = atomicAdd(&pos[dst], 1);
  csr_src[p] = src;
}

// ======================= split kernels (f32 -> bf16 hi/lo) ===================

__global__ void k_split_x(const float* __restrict__ x,
                          unsigned short* __restrict__ xh,
                          unsigned short* __restrict__ xl, int total8){
  int idx = blockIdx.x*256 + threadIdx.x;
  if (idx >= total8) return;
  const float4* p = (const float4*)x + (size_t)idx*2;
  float4 f0 = p[0], f1 = p[1];
  float f[8] = {f0.x,f0.y,f0.z,f0.w,f1.x,f1.y,f1.z,f1.w};
  unsigned h[8], lo[8];
  #pragma unroll
  for (int j = 0; j < 8; ++j){
    h[j] = f2bf(f[j]);
    lo[j] = f2bf(f[j] - bf2f((unsigned short)h[j]));
  }
  uint4 hv = make_uint4(h[0]|(h[1]<<16), h[2]|(h[3]<<16), h[4]|(h[5]<<16), h[6]|(h[7]<<16));
  uint4 lv = make_uint4(lo[0]|(lo[1]<<16), lo[2]|(lo[3]<<16), lo[4]|(lo[5]<<16), lo[6]|(lo[7]<<16));
  *(uint4*)(xh + (size_t)idx*8) = hv;
  *(uint4*)(xl + (size_t)idx*8) = lv;
}

__global__ void k_split_wt(const float* __restrict__ W0, const float* __restrict__ W1,
                           int split, int K, int Nf,
                           unsigned short* __restrict__ th,
                           unsigned short* __restrict__ tl){
  int kg8 = K >> 3;
  int idx = blockIdx.x*256 + threadIdx.x;
  if (idx >= Nf*kg8) return;
  int n  = idx / kg8;
  int kg = (idx - n*kg8) * 8;
  const float* src; int ld;
  if (n < split){ src = W0 + n;          ld = split; }
  else          { src = W1 + (n - split); ld = Nf - split; }
  unsigned h[8], lo[8];
  #pragma unroll
  for (int j = 0; j < 8; ++j){
    float v = src[(size_t)(kg + j) * ld];
    h[j]  = f2bf(v);
    lo[j] = f2bf(v - bf2f((unsigned short)h[j]));
  }
  uint4 hv = make_uint4(h[0]|(h[1]<<16), h[2]|(h[3]<<16), h[4]|(h[5]<<16), h[6]|(h[7]<<16));
  uint4 lv = make_uint4(lo[0]|(lo[1]<<16), lo[2]|(lo[3]<<16), lo[4]|(lo[5]<<16), lo[6]|(lo[7]<<16));
  *(uint4*)(th + (size_t)n*K + kg) = hv;
  *(uint4*)(tl + (size_t)n*K + kg) = lv;
}

// ======================= MFMA GEMM (split-bf16 x3) ==========================

__global__ __launch_bounds__(256) void k_gemm_mfma(
    const unsigned short* __restrict__ Xh, const unsigned short* __restrict__ Xl,
    int Kd, int M,
    const unsigned short* __restrict__ Wth, const unsigned short* __restrict__ Wtl,
    int Nf, int split,
    const float* __restrict__ b0, const float* __restrict__ b1,
    float* __restrict__ O0, float* __restrict__ O1, int ldO)
{
  __shared__ unsigned short ldsA[128*64];
  __shared__ unsigned short ldsB[128*64];
  char* cA = (char*)ldsA;
  char* cB = (char*)ldsB;

  int t = threadIdx.x;
  int w = t >> 6, l = t & 63;
  int wr = w >> 1, wc = w & 1;
  int lr = l & 15, lg = l >> 4;

  int row0 = blockIdx.x * 128;
  int col0 = blockIdx.y * 128;

  f32x4 acc[4][4];
  #pragma unroll
  for (int i = 0; i < 4; ++i)
    #pragma unroll
    for (int j = 0; j < 4; ++j) acc[i][j] = (f32x4){0.f,0.f,0.f,0.f};

  int sr_off = l >> 3;
  int slot   = 0;

  for (int k0 = 0; k0 < Kd; k0 += 32){
    __syncthreads();
    #pragma unroll
    for (int i = 0; i < 4; ++i){
      int chunk = w*4 + i;
      int r = chunk*8 + sr_off;
      slot = (l & 7) ^ (r & 7);
      int h = slot >> 2, g = slot & 3;
      int row = row0 + r; if (row > M-1) row = M-1;
      const unsigned short* src = (h ? Xl : Xh) + (size_t)row*Kd + k0 + g*8;
      __builtin_amdgcn_global_load_lds(
          (const __attribute__((address_space(1))) void*)src,
          (__attribute__((address_space(3))) void*)(cA + chunk*1024), 16, 0, 0);
    }
    #pragma unroll
    for (int i = 0; i < 4; ++i){
      int chunk = w*4 + i;
      int r = chunk*8 + sr_off;
      slot = (l & 7) ^ (r & 7);
      int h = slot >> 2, g = slot & 3;
      int n = col0 + r; if (n > Nf-1) n = Nf-1;
      const unsigned short* src = (h ? Wtl : Wth) + (size_t)n*Kd + k0 + g*8;
      __builtin_amdgcn_global_load_lds(
          (const __attribute__((address_space(1))) void*)src,
          (__attribute__((address_space(3))) void*)(cB + chunk*1024), 16, 0, 0);
    }
    __syncthreads();

    short8 ah[4], al[4], bh[4], bl[4];
    #pragma unroll
    for (int mi = 0; mi < 4; ++mi){
      int r = wr*64 + mi*16 + lr;
      unsigned sw = (unsigned)((r & 7) << 4);
      unsigned ba = (unsigned)(r*128 + lg*16);
      ah[mi] = *(const short8*)(cA + (ba ^ sw));
      al[mi] = *(const short8*)(cA + ((ba + 64) ^ sw));
    }
    #pragma unroll
    for (int ni = 0; ni < 4; ++ni){
      int n = wc*64 + ni*16 + lr;
      unsigned sw = (unsigned)((n & 7) << 4);
      unsigned bb = (unsigned)(n*128 + lg*16);
      bh[ni] = *(const short8*)(cB + (bb ^ sw));
      bl[ni] = *(const short8*)(cB + ((bb + 64) ^ sw));
    }
    #pragma unroll
    for (int mi = 0; mi < 4; ++mi)
      #pragma unroll
      for (int ni = 0; ni < 4; ++ni){
        acc[mi][ni] = __builtin_amdgcn_mfma_f32_16x16x32_bf16(ah[mi], bh[ni], acc[mi][ni], 0, 0, 0);
        acc[mi][ni] = __builtin_amdgcn_mfma_f32_16x16x32_bf16(ah[mi], bl[ni], acc[mi][ni], 0, 0, 0);
        acc[mi][ni] = __builtin_amdgcn_mfma_f32_16x16x32_bf16(al[mi], bh[ni], acc[mi][ni], 0, 0, 0);
      }
  }

  #pragma unroll
  for (int ni = 0; ni < 4; ++ni){
    int col = col0 + wc*64 + ni*16 + lr;
    if (col >= Nf) continue;
    float bias; float* O;
    if (col < split){ bias = b0[col];         O = O0 + col; }
    else            { bias = b1[col - split]; O = O1 + (col - split); }
    #pragma unroll
    for (int mi = 0; mi < 4; ++mi){
      int rbase = row0 + wr*64 + mi*16 + lg*4;
      #pragma unroll
      for (int q = 0; q < 4; ++q){
        int row = rbase + q;
        if (row < M) O[(size_t)row * ldO] = acc[mi][ni][q] + bias;
      }
    }
  }
}

// ======================= Layer 1 aggregation (fused softmax) =================
// 32 lanes per node (2 nodes/wave). Lane (h,li): h=l>>3, li=l&7 owns channels
// h*32+4*li..+3 (float4). Defer-max online softmax (THR=8). Writes h as bf16
// hi/lo for the layer-2 MFMA GEMM.
__global__ __launch_bounds__(256) void k_agg1(
    const float* __restrict__ xl, const float* __restrict__ xr,
    const int* __restrict__ rowptr, const int* __restrict__ deg,
    const int* __restrict__ csr, const float* __restrict__ att,
    const float* __restrict__ bias,
    unsigned short* __restrict__ Hh, unsigned short* __restrict__ Hl)
{
  int node = blockIdx.x*8 + (threadIdx.x >> 5);
  int l  = threadIdx.x & 31;
  int h  = l >> 3;
  int li = l & 7;
  int c0 = h*32 + li*4;

  float4 av  = *(const float4*)(att + c0);
  float4 xrv = *(const float4*)(xr + (size_t)node*128 + c0);

  int start = rowptr[node], cnt = deg[node];

  int sp = csr[start];
  float4 vn = *(const float4*)(xl + (size_t)sp*128 + c0);
  int sn = (cnt > 1) ? csr[start + 1] : sp;

  float m = -INFINITY, s = 0.f;
  float4 acc = make_float4(0.f, 0.f, 0.f, 0.f);

  for (int i = 0; i < cnt; ++i){
    float4 v = vn;
    int scur = sn;
    vn = *(const float4*)(xl + (size_t)scur*128 + c0);
    int i2 = i + 2;
    sn = csr[start + ((i2 < cnt) ? i2 : (cnt - 1))];

    float g0 = v.x + xrv.x; g0 = fmaxf(g0, SLOPE*g0);
    float g1 = v.y + xrv.y; g1 = fmaxf(g1, SLOPE*g1);
    float g2 = v.z + xrv.z; g2 = fmaxf(g2, SLOPE*g2);
    float g3 = v.w + xrv.w; g3 = fmaxf(g3, SLOPE*g3);
    float p = g0*av.x + g1*av.y + g2*av.z + g3*av.w;
    p += __shfl_xor(p, 1); p += __shfl_xor(p, 2); p += __shfl_xor(p, 4);

    if (__any(p > m + 8.f)){           // defer-max: rescale rarely
      float mn = fmaxf(m, p);
      float sc = __expf(m - mn);
      s *= sc;
      acc.x *= sc; acc.y *= sc; acc.z *= sc; acc.w *= sc;
      m = mn;
    }
    float wgt = __expf(p - m);         // bounded by e^8
    s += wgt;
    acc.x += wgt*v.x;
    acc.y += wgt*v.y;
    acc.z += wgt*v.z;
    acc.w += wgt*v.w;
  }

  float inv = 1.f/(s + 1e-16f);
  float4 b4 = *(const float4*)(bias + c0);
  float o[4];
  o[0] = acc.x*inv + b4.x;
  o[1] = acc.y*inv + b4.y;
  o[2] = acc.z*inv + b4.z;
  o[3] = acc.w*inv + b4.w;
  unsigned hh[4], hl[4];
  #pragma unroll
  for (int j = 0; j < 4; ++j){
    float e = o[j] > 0.f ? o[j] : (__expf(o[j]) - 1.f);   // ELU
    hh[j] = f2bf(e);
    hl[j] = f2bf(e - bf2f((unsigned short)hh[j]));
  }
  *(uint2*)(Hh + (size_t)node*128 + c0) = make_uint2(hh[0]|(hh[1]<<16), hh[2]|(hh[3]<<16));
  *(uint2*)(Hl + (size_t)node*128 + c0) = make_uint2(hl[0]|(hl[1]<<16), hl[2]|(hl[3]<<16));
}

// ======================= Layer 2 aggregation (head-mean) =====================
// v2: 2 nodes/wave, 32 lanes/node, ZERO idle lanes. Lane (h,li): h=hl>>3,
// li=hl&7 owns float4 at h*40+li*4 plus scalar at h*40+32+li (5 ch total).
// Logit reduce = 3 shfl over 8-lane head group. Defer-max softmax. Head-mean
// via shfl_xor 8,16 within the 32-lane half.
__global__ __launch_bounds__(256) void k_agg2(
    const float* __restrict__ xl, const float* __restrict__ xr,
    const int* __restrict__ rowptr, const int* __restrict__ deg,
    const int* __restrict__ csr, const float* __restrict__ att,
    const float* __restrict__ bias, float* __restrict__ out)
{
  int node = blockIdx.x*8 + (threadIdx.x >> 5);
  int hl   = threadIdx.x & 31;
  int h  = hl >> 3;
  int li = hl & 7;
  int c4 = h*40 + li*4;
  int cs = h*40 + 32 + li;

  float4 a4 = *(const float4*)(att + c4);
  float  as = att[cs];
  const float* xrp = xr + (size_t)node*160;
  float4 r4 = *(const float4*)(xrp + c4);
  float  rs = xrp[cs];

  int start = rowptr[node], cnt = deg[node];

  int sp = csr[start];
  {  }
  const float* xp0 = xl + (size_t)sp*160;
  float4 v4n = *(const float4*)(xp0 + c4);
  float  vsn = xp0[cs];
  int sn = (cnt > 1) ? csr[start + 1] : sp;

  float m = -INFINITY, s = 0.f;
  float4 ac4 = make_float4(0.f,0.f,0.f,0.f);
  float  acs = 0.f;

  for (int i = 0; i < cnt; ++i){
    float4 v4 = v4n; float vs = vsn;
    int scur = sn;
    const float* xp = xl + (size_t)scur*160;
    v4n = *(const float4*)(xp + c4);
    vsn = xp[cs];
    int i2 = i + 2;
    sn = csr[start + ((i2 < cnt) ? i2 : (cnt - 1))];

    float g0 = v4.x + r4.x; g0 = fmaxf(g0, SLOPE*g0);
    float g1 = v4.y + r4.y; g1 = fmaxf(g1, SLOPE*g1);
    float g2 = v4.z + r4.z; g2 = fmaxf(g2, SLOPE*g2);
    float g3 = v4.w + r4.w; g3 = fmaxf(g3, SLOPE*g3);
    float g4 = vs   + rs;   g4 = fmaxf(g4, SLOPE*g4);
    float p = g0*a4.x + g1*a4.y + g2*a4.z + g3*a4.w + g4*as;
    p += __shfl_xor(p, 1); p += __shfl_xor(p, 2); p += __shfl_xor(p, 4);

    if (__any(p > m + 8.f)){           // defer-max
      float mn = fmaxf(m, p);
      float sc = __expf(m - mn);
      s *= sc;
      ac4.x *= sc; ac4.y *= sc; ac4.z *= sc; ac4.w *= sc; acs *= sc;
      m = mn;
    }
    float wgt = __expf(p - m);
    s += wgt;
    ac4.x += wgt*v4.x;
    ac4.y += wgt*v4.y;
    ac4.z += wgt*v4.z;
    ac4.w += wgt*v4.w;
    acs   += wgt*vs;
  }

  float inv = 1.f/(s + 1e-16f);
  float o0 = ac4.x*inv, o1 = ac4.y*inv, o2 = ac4.z*inv, o3 = ac4.w*inv, o4 = acs*inv;
  // head mean: sum the 4 head groups (xor 8, 16 stay within the 32-lane half)
  o0 += __shfl_xor(o0, 8); o0 += __shfl_xor(o0, 16);
  o1 += __shfl_xor(o1, 8); o1 += __shfl_xor(o1, 16);
  o2 += __shfl_xor(o2, 8); o2 += __shfl_xor(o2, 16);
  o3 += __shfl_xor(o3, 8); o3 += __shfl_xor(o3, 16);
  o4 += __shfl_xor(o4, 8); o4 += __shfl_xor(o4, 16);
  if (h == 0){
    float4 b4 = *(const float4*)(bias + li*4);
    float4 r = make_float4(0.25f*o0 + b4.x, 0.25f*o1 + b4.y,
                           0.25f*o2 + b4.z, 0.25f*o3 + b4.w);
    *(float4*)(out + (size_t)node*OUTD + li*4) = r;
    out[(size_t)node*OUTD + 32 + li] = 0.25f*o4 + bias[32 + li];
  }
}

// ======================= launch =======================

extern "C" void kernel_launch(void* const* d_in, const int* in_sizes, int n_in,
                              void* d_out, int out_size, void* d_ws, size_t ws_size,
                              hipStream_t stream)
{
  const float* x     = (const float*)d_in[0];
  const int*   ei    = (const int*)  d_in[1];
  const float* Wl1   = (const float*)d_in[2];
  const float* bl1   = (const float*)d_in[3];
  const float* Wr1   = (const float*)d_in[4];
  const float* br1   = (const float*)d_in[5];
  const float* att1  = (const float*)d_in[6];
  const float* bias1 = (const float*)d_in[7];
  const float* Wl2   = (const float*)d_in[8];
  const float* bl2   = (const float*)d_in[9];
  const float* Wr2   = (const float*)d_in[10];
  const float* br2   = (const float*)d_in[11];
  const float* att2  = (const float*)d_in[12];
  const float* bias2 = (const float*)d_in[13];
  float* out = (float*)d_out;

  char* w = (char*)d_ws;
  size_t off = 0;
  auto alloc = [&](size_t bytes) -> void* {
    void* p = w + off;
    off = (off + bytes + 255) & ~(size_t)255;
    return p;
  };

  int* deg    = (int*)alloc((size_t)NNODES*4);
  int* rowptr = (int*)alloc((size_t)NNODES*4);
  int* pos    = (int*)alloc((size_t)NNODES*4);
  int* bsum   = (int*)alloc(256*4);
  int* boff   = (int*)alloc(256*4);
  int* csr    = (int*)alloc((size_t)ET*4);
  float* slabA = (float*)alloc((size_t)NNODES*160*4);  // xl1 then xl2
  float* slabB = (float*)alloc((size_t)NNODES*160*4);  // xr1 then xr2
  unsigned short* Xh = (unsigned short*)alloc((size_t)NNODES*256*2);  // later Hh
  unsigned short* Xl = (unsigned short*)alloc((size_t)NNODES*256*2);  // later Hl
  unsigned short* W1th = (unsigned short*)alloc((size_t)256*256*2);
  unsigned short* W1tl = (unsigned short*)alloc((size_t)256*256*2);
  unsigned short* W2th = (unsigned short*)alloc((size_t)320*128*2);
  unsigned short* W2tl = (unsigned short*)alloc((size_t)320*128*2);
  unsigned short* Hh = Xh;   // reuse: X splits dead after gemm1
  unsigned short* Hl = Xl;

  const int NB = (NNODES + 255)/256;         // 196
  const int EB = (ET + 255)/256;             // 3321

  // CSR
  hipMemsetAsync(deg, 0, (size_t)NNODES*4, stream);
  k_count<<<EB, 256, 0, stream>>>(ei, deg);
  k_bsum <<<NB, 256, 0, stream>>>(deg, bsum);
  k_scanb<<<1, 256, 0, stream>>>(bsum, NB, boff);
  k_scanw<<<NB, 256, 0, stream>>>(deg, boff, rowptr);
  hipMemcpyAsync(pos, rowptr, (size_t)NNODES*4, hipMemcpyDeviceToDevice, stream);
  k_scatter<<<EB, 256, 0, stream>>>(ei, pos, csr);

  // splits
  k_split_x<<<(NNODES*256/8 + 255)/256, 256, 0, stream>>>(x, Xh, Xl, NNODES*256/8);
  k_split_wt<<<(256*32 + 255)/256, 256, 0, stream>>>(Wl1, Wr1, 128, 256, 256, W1th, W1tl);
  k_split_wt<<<(320*16 + 255)/256, 256, 0, stream>>>(Wl2, Wr2, 160, 128, 320, W2th, W2tl);

  // layer 1
  dim3 g1((NNODES + 127)/128, 2);   // N=256
  k_gemm_mfma<<<g1, 256, 0, stream>>>(Xh, Xl, 256, NNODES,
                                      W1th, W1tl, 256, 128,
                                      bl1, br1, slabA, slabB, 128);
  k_agg1<<<6250, 256, 0, stream>>>(slabA, slabB, rowptr, deg, csr, att1, bias1, Hh, Hl);

  // layer 2
  dim3 g2((NNODES + 127)/128, 3);   // N=320 (last block half-masked)
  k_gemm_mfma<<<g2, 256, 0, stream>>>(Hh, Hl, 128, NNODES,
                                      W2th, W2tl, 320, 160,
                                      bl2, br2, slabA, slabB, 160);
  k_agg2<<<NNODES/8, 256, 0, stream>>>(slabA, slabB, rowptr, deg, csr, att2, bias2, out);
}

// Round 6
// 448.644 us; speedup vs baseline: 1.3491x; 1.0024x over previous
//
#include <hip/hip_runtime.h>
#include <math.h>

#define NNODES 50000
#define NEDGES 800000
#define ET (NNODES + NEDGES)   // 850000 with self loops
#define SLOPE 0.2f
#define OUTD 40

typedef __attribute__((ext_vector_type(8))) short short8;
typedef __attribute__((ext_vector_type(4))) float f32x4;

// float -> bf16 bits, round-to-nearest-even
__device__ inline unsigned short f2bf(float f){
  unsigned u = __float_as_uint(f);
  unsigned r = (u + 0x7FFFu + ((u >> 16) & 1u)) >> 16;
  return (unsigned short)r;
}
__device__ inline float bf2f(unsigned short h){
  return __uint_as_float(((unsigned)h) << 16);
}

// ======================= CSR build =======================

__global__ void k_count(const int* __restrict__ ei, int* __restrict__ deg){
  int e = blockIdx.x*256 + threadIdx.x;
  if (e >= ET) return;
  int dst = (e < NEDGES) ? ei[NEDGES + e] : (e - NEDGES);
  atomicAdd(&deg[dst], 1);
}

__global__ void k_bsum(const int* __restrict__ deg, int* __restrict__ bsum){
  int i = blockIdx.x*256 + threadIdx.x;
  int v = (i < NNODES) ? deg[i] : 0;
  for (int o = 1; o < 64; o <<= 1) v += __shfl_xor(v, o);
  __shared__ int ws[4];
  if ((threadIdx.x & 63) == 0) ws[threadIdx.x >> 6] = v;
  __syncthreads();
  if (threadIdx.x == 0) bsum[blockIdx.x] = ws[0] + ws[1] + ws[2] + ws[3];
}

__global__ void k_scanb(const int* __restrict__ bsum, int nb, int* __restrict__ boff){
  __shared__ int sm[256];
  int t = threadIdx.x;
  int v = (t < nb) ? bsum[t] : 0;
  sm[t] = v; __syncthreads();
  for (int d = 1; d < 256; d <<= 1){
    int x = (t >= d) ? sm[t - d] : 0;
    __syncthreads();
    sm[t] += x;
    __syncthreads();
  }
  if (t < nb) boff[t] = sm[t] - v;   // exclusive
}

__global__ void k_scanw(const int* __restrict__ deg, const int* __restrict__ boff,
                        int* __restrict__ rowptr){
  __shared__ int sm[256];
  int t = threadIdx.x, i = blockIdx.x*256 + t;
  int v = (i < NNODES) ? deg[i] : 0;
  sm[t] = v; __syncthreads();
  for (int d = 1; d < 256; d <<= 1){
    int x = (t >= d) ? sm[t - d] : 0;
    __syncthreads();
    sm[t] += x;
    __syncthreads();
  }
  if (i < NNODES) rowptr[i] = boff[blockIdx.x] + sm[t] - v;  // exclusive
}

__global__ void k_scatter(const int* __restrict__ ei, int* __restrict__ pos,
                          int* __restrict__ csr_src){
  int e = blockIdx.x*256 + threadIdx.x;
  if (e >= ET) return;
  int src, dst;
  if (e < NEDGES){ src = ei[e]; dst = ei[NEDGES + e]; }
  else           { src = dst = e - NEDGES; }
  int p = atomicAdd(&pos[dst], 1);
  csr_src[p] = src;
}

// ======================= split kernels (f32 -> bf16 hi/lo) ===================

__global__ void k_split_x(const float* __restrict__ x,
                          unsigned short* __restrict__ xh,
                          unsigned short* __restrict__ xl, int total8){
  int idx = blockIdx.x*256 + threadIdx.x;
  if (idx >= total8) return;
  const float4* p = (const float4*)x + (size_t)idx*2;
  float4 f0 = p[0], f1 = p[1];
  float f[8] = {f0.x,f0.y,f0.z,f0.w,f1.x,f1.y,f1.z,f1.w};
  unsigned h[8], lo[8];
  #pragma unroll
  for (int j = 0; j < 8; ++j){
    h[j] = f2bf(f[j]);
    lo[j] = f2bf(f[j] - bf2f((unsigned short)h[j]));
  }
  uint4 hv = make_uint4(h[0]|(h[1]<<16), h[2]|(h[3]<<16), h[4]|(h[5]<<16), h[6]|(h[7]<<16));
  uint4 lv = make_uint4(lo[0]|(lo[1]<<16), lo[2]|(lo[3]<<16), lo[4]|(lo[5]<<16), lo[6]|(lo[7]<<16));
  *(uint4*)(xh + (size_t)idx*8) = hv;
  *(uint4*)(xl + (size_t)idx*8) = lv;
}

__global__ void k_split_wt(const float* __restrict__ W0, const float* __restrict__ W1,
                           int split, int K, int Nf,
                           unsigned short* __restrict__ th,
                           unsigned short* __restrict__ tl){
  int kg8 = K >> 3;
  int idx = blockIdx.x*256 + threadIdx.x;
  if (idx >= Nf*kg8) return;
  int n  = idx / kg8;
  int kg = (idx - n*kg8) * 8;
  const float* src; int ld;
  if (n < split){ src = W0 + n;          ld = split; }
  else          { src = W1 + (n - split); ld = Nf - split; }
  unsigned h[8], lo[8];
  #pragma unroll
  for (int j = 0; j < 8; ++j){
    float v = src[(size_t)(kg + j) * ld];
    h[j]  = f2bf(v);
    lo[j] = f2bf(v - bf2f((unsigned short)h[j]));
  }
  uint4 hv = make_uint4(h[0]|(h[1]<<16), h[2]|(h[3]<<16), h[4]|(h[5]<<16), h[6]|(h[7]<<16));
  uint4 lv = make_uint4(lo[0]|(lo[1]<<16), lo[2]|(lo[3]<<16), lo[4]|(lo[5]<<16), lo[6]|(lo[7]<<16));
  *(uint4*)(th + (size_t)n*K + kg) = hv;
  *(uint4*)(tl + (size_t)n*K + kg) = lv;
}

// ======================= MFMA GEMM (split-bf16 x3) ==========================

__global__ __launch_bounds__(256) void k_gemm_mfma(
    const unsigned short* __restrict__ Xh, const unsigned short* __restrict__ Xl,
    int Kd, int M,
    const unsigned short* __restrict__ Wth, const unsigned short* __restrict__ Wtl,
    int Nf, int split,
    const float* __restrict__ b0, const float* __restrict__ b1,
    float* __restrict__ O0, float* __restrict__ O1, int ldO)
{
  __shared__ unsigned short ldsA[128*64];
  __shared__ unsigned short ldsB[128*64];
  char* cA = (char*)ldsA;
  char* cB = (char*)ldsB;

  int t = threadIdx.x;
  int w = t >> 6, l = t & 63;
  int wr = w >> 1, wc = w & 1;
  int lr = l & 15, lg = l >> 4;

  int row0 = blockIdx.x * 128;
  int col0 = blockIdx.y * 128;

  f32x4 acc[4][4];
  #pragma unroll
  for (int i = 0; i < 4; ++i)
    #pragma unroll
    for (int j = 0; j < 4; ++j) acc[i][j] = (f32x4){0.f,0.f,0.f,0.f};

  int sr_off = l >> 3;
  int slot   = 0;

  for (int k0 = 0; k0 < Kd; k0 += 32){
    __syncthreads();
    #pragma unroll
    for (int i = 0; i < 4; ++i){
      int chunk = w*4 + i;
      int r = chunk*8 + sr_off;
      slot = (l & 7) ^ (r & 7);
      int h = slot >> 2, g = slot & 3;
      int row = row0 + r; if (row > M-1) row = M-1;
      const unsigned short* src = (h ? Xl : Xh) + (size_t)row*Kd + k0 + g*8;
      __builtin_amdgcn_global_load_lds(
          (const __attribute__((address_space(1))) void*)src,
          (__attribute__((address_space(3))) void*)(cA + chunk*1024), 16, 0, 0);
    }
    #pragma unroll
    for (int i = 0; i < 4; ++i){
      int chunk = w*4 + i;
      int r = chunk*8 + sr_off;
      slot = (l & 7) ^ (r & 7);
      int h = slot >> 2, g = slot & 3;
      int n = col0 + r; if (n > Nf-1) n = Nf-1;
      const unsigned short* src = (h ? Wtl : Wth) + (size_t)n*Kd + k0 + g*8;
      __builtin_amdgcn_global_load_lds(
          (const __attribute__((address_space(1))) void*)src,
          (__attribute__((address_space(3))) void*)(cB + chunk*1024), 16, 0, 0);
    }
    __syncthreads();

    short8 ah[4], al[4], bh[4], bl[4];
    #pragma unroll
    for (int mi = 0; mi < 4; ++mi){
      int r = wr*64 + mi*16 + lr;
      unsigned sw = (unsigned)((r & 7) << 4);
      unsigned ba = (unsigned)(r*128 + lg*16);
      ah[mi] = *(const short8*)(cA + (ba ^ sw));
      al[mi] = *(const short8*)(cA + ((ba + 64) ^ sw));
    }
    #pragma unroll
    for (int ni = 0; ni < 4; ++ni){
      int n = wc*64 + ni*16 + lr;
      unsigned sw = (unsigned)((n & 7) << 4);
      unsigned bb = (unsigned)(n*128 + lg*16);
      bh[ni] = *(const short8*)(cB + (bb ^ sw));
      bl[ni] = *(const short8*)(cB + ((bb + 64) ^ sw));
    }
    #pragma unroll
    for (int mi = 0; mi < 4; ++mi)
      #pragma unroll
      for (int ni = 0; ni < 4; ++ni){
        acc[mi][ni] = __builtin_amdgcn_mfma_f32_16x16x32_bf16(ah[mi], bh[ni], acc[mi][ni], 0, 0, 0);
        acc[mi][ni] = __builtin_amdgcn_mfma_f32_16x16x32_bf16(ah[mi], bl[ni], acc[mi][ni], 0, 0, 0);
        acc[mi][ni] = __builtin_amdgcn_mfma_f32_16x16x32_bf16(al[mi], bh[ni], acc[mi][ni], 0, 0, 0);
      }
  }

  #pragma unroll
  for (int ni = 0; ni < 4; ++ni){
    int col = col0 + wc*64 + ni*16 + lr;
    if (col >= Nf) continue;
    float bias; float* O;
    if (col < split){ bias = b0[col];         O = O0 + col; }
    else            { bias = b1[col - split]; O = O1 + (col - split); }
    #pragma unroll
    for (int mi = 0; mi < 4; ++mi){
      int rbase = row0 + wr*64 + mi*16 + lg*4;
      #pragma unroll
      for (int q = 0; q < 4; ++q){
        int row = rbase + q;
        if (row < M) O[(size_t)row * ldO] = acc[mi][ni][q] + bias;
      }
    }
  }
}

// ======================= Layer 1 aggregation (fused softmax) =================
// 32 lanes/node (2 nodes/wave). Lane (h,li): h=l>>3, li=l&7 owns channels
// h*32+4*li..+3 (float4). Edge-PAIR loop: next pair's rows issued before this
// pair's compute (2-edge lookahead); indices prefetched 4 ahead. Tail edge
// handled branch-free via p1=-inf (weight 0). Defer-max softmax (THR=8).
__global__ __launch_bounds__(256) void k_agg1(
    const float* __restrict__ xl, const float* __restrict__ xr,
    const int* __restrict__ rowptr, const int* __restrict__ deg,
    const int* __restrict__ csr, const float* __restrict__ att,
    const float* __restrict__ bias,
    unsigned short* __restrict__ Hh, unsigned short* __restrict__ Hl)
{
  int node = blockIdx.x*8 + (threadIdx.x >> 5);
  int l  = threadIdx.x & 31;
  int h  = l >> 3;
  int li = l & 7;
  int c0 = h*32 + li*4;

  float4 av  = *(const float4*)(att + c0);
  float4 xrv = *(const float4*)(xr + (size_t)node*128 + c0);

  int start = rowptr[node], cnt = deg[node];
  int last = cnt - 1;

  // prologue: rows for edges 0,1 ; indices for edges 2,3 (all clamped)
  int i0 = csr[start];
  int i1 = csr[start + min(1, last)];
  float4 r0 = *(const float4*)(xl + (size_t)i0*128 + c0);
  float4 r1 = *(const float4*)(xl + (size_t)i1*128 + c0);
  int ia = csr[start + min(2, last)];
  int ib = csr[start + min(3, last)];

  float m = -INFINITY, s = 0.f;
  float4 acc = make_float4(0.f, 0.f, 0.f, 0.f);

  for (int j = 0; j < cnt; j += 2){
    float4 v0 = r0, v1 = r1;
    // issue next pair's rows + prefetch indices 4 ahead
    r0 = *(const float4*)(xl + (size_t)ia*128 + c0);
    r1 = *(const float4*)(xl + (size_t)ib*128 + c0);
    ia = csr[start + min(j + 4, last)];
    ib = csr[start + min(j + 5, last)];

    float g0, g1, g2, g3;
    g0 = v0.x + xrv.x; g0 = fmaxf(g0, SLOPE*g0);
    g1 = v0.y + xrv.y; g1 = fmaxf(g1, SLOPE*g1);
    g2 = v0.z + xrv.z; g2 = fmaxf(g2, SLOPE*g2);
    g3 = v0.w + xrv.w; g3 = fmaxf(g3, SLOPE*g3);
    float p0 = g0*av.x + g1*av.y + g2*av.z + g3*av.w;
    g0 = v1.x + xrv.x; g0 = fmaxf(g0, SLOPE*g0);
    g1 = v1.y + xrv.y; g1 = fmaxf(g1, SLOPE*g1);
    g2 = v1.z + xrv.z; g2 = fmaxf(g2, SLOPE*g2);
    g3 = v1.w + xrv.w; g3 = fmaxf(g3, SLOPE*g3);
    float p1 = g0*av.x + g1*av.y + g2*av.z + g3*av.w;

    p0 += __shfl_xor(p0, 1); p1 += __shfl_xor(p1, 1);
    p0 += __shfl_xor(p0, 2); p1 += __shfl_xor(p1, 2);
    p0 += __shfl_xor(p0, 4); p1 += __shfl_xor(p1, 4);
    if (j + 1 >= cnt) p1 = -INFINITY;   // tail edge contributes weight 0

    float pm = fmaxf(p0, p1);
    if (__any(pm > m + 8.f)){           // defer-max: rescale rarely
      float mn = fmaxf(m, pm);
      float sc = __expf(m - mn);
      s *= sc;
      acc.x *= sc; acc.y *= sc; acc.z *= sc; acc.w *= sc;
      m = mn;
    }
    float w0 = __expf(p0 - m);
    float w1 = __expf(p1 - m);
    s += w0 + w1;
    acc.x += w0*v0.x + w1*v1.x;
    acc.y += w0*v0.y + w1*v1.y;
    acc.z += w0*v0.z + w1*v1.z;
    acc.w += w0*v0.w + w1*v1.w;
  }

  float inv = 1.f/(s + 1e-16f);
  float4 b4 = *(const float4*)(bias + c0);
  float o[4];
  o[0] = acc.x*inv + b4.x;
  o[1] = acc.y*inv + b4.y;
  o[2] = acc.z*inv + b4.z;
  o[3] = acc.w*inv + b4.w;
  unsigned hh[4], hlv[4];
  #pragma unroll
  for (int j = 0; j < 4; ++j){
    float e = o[j] > 0.f ? o[j] : (__expf(o[j]) - 1.f);   // ELU
    hh[j]  = f2bf(e);
    hlv[j] = f2bf(e - bf2f((unsigned short)hh[j]));
  }
  *(uint2*)(Hh + (size_t)node*128 + c0) = make_uint2(hh[0]|(hh[1]<<16), hh[2]|(hh[3]<<16));
  *(uint2*)(Hl + (size_t)node*128 + c0) = make_uint2(hlv[0]|(hlv[1]<<16), hlv[2]|(hlv[3]<<16));
}

// ======================= Layer 2 aggregation (head-mean) =====================
// 2 nodes/wave, 32 lanes/node. Lane (h,li): h=hl>>3, li=hl&7 owns float4 at
// h*40+li*4 plus scalar at h*40+32+li. Edge-pair loop with 2-edge lookahead,
// branch-free tail (p1=-inf), defer-max softmax. Head-mean via shfl 8,16.
__global__ __launch_bounds__(256) void k_agg2(
    const float* __restrict__ xl, const float* __restrict__ xr,
    const int* __restrict__ rowptr, const int* __restrict__ deg,
    const int* __restrict__ csr, const float* __restrict__ att,
    const float* __restrict__ bias, float* __restrict__ out)
{
  int node = blockIdx.x*8 + (threadIdx.x >> 5);
  int hl   = threadIdx.x & 31;
  int h  = hl >> 3;
  int li = hl & 7;
  int c4 = h*40 + li*4;
  int cs = h*40 + 32 + li;

  float4 a4 = *(const float4*)(att + c4);
  float  as = att[cs];
  const float* xrp = xr + (size_t)node*160;
  float4 r4 = *(const float4*)(xrp + c4);
  float  rs = xrp[cs];

  int start = rowptr[node], cnt = deg[node];
  int last = cnt - 1;

  int i0 = csr[start];
  int i1 = csr[start + min(1, last)];
  const float* q0 = xl + (size_t)i0*160;
  const float* q1 = xl + (size_t)i1*160;
  float4 rv0 = *(const float4*)(q0 + c4); float sv0 = q0[cs];
  float4 rv1 = *(const float4*)(q1 + c4); float sv1 = q1[cs];
  int ia = csr[start + min(2, last)];
  int ib = csr[start + min(3, last)];

  float m = -INFINITY, s = 0.f;
  float4 ac4 = make_float4(0.f,0.f,0.f,0.f);
  float  acs = 0.f;

  for (int j = 0; j < cnt; j += 2){
    float4 v40 = rv0, v41 = rv1;
    float  vs0 = sv0, vs1 = sv1;
    const float* qa = xl + (size_t)ia*160;
    const float* qb = xl + (size_t)ib*160;
    rv0 = *(const float4*)(qa + c4); sv0 = qa[cs];
    rv1 = *(const float4*)(qb + c4); sv1 = qb[cs];
    ia = csr[start + min(j + 4, last)];
    ib = csr[start + min(j + 5, last)];

    float g0, g1, g2, g3, g4;
    g0 = v40.x + r4.x; g0 = fmaxf(g0, SLOPE*g0);
    g1 = v40.y + r4.y; g1 = fmaxf(g1, SLOPE*g1);
    g2 = v40.z + r4.z; g2 = fmaxf(g2, SLOPE*g2);
    g3 = v40.w + r4.w; g3 = fmaxf(g3, SLOPE*g3);
    g4 = vs0   + rs;   g4 = fmaxf(g4, SLOPE*g4);
    float p0 = g0*a4.x + g1*a4.y + g2*a4.z + g3*a4.w + g4*as;
    g0 = v41.x + r4.x; g0 = fmaxf(g0, SLOPE*g0);
    g1 = v41.y + r4.y; g1 = fmaxf(g1, SLOPE*g1);
    g2 = v41.z + r4.z; g2 = fmaxf(g2, SLOPE*g2);
    g3 = v41.w + r4.w; g3 = fmaxf(g3, SLOPE*g3);
    g4 = vs1   + rs;   g4 = fmaxf(g4, SLOPE*g4);
    float p1 = g0*a4.x + g1*a4.y + g2*a4.z + g3*a4.w + g4*as;

    p0 += __shfl_xor(p0, 1); p1 += __shfl_xor(p1, 1);
    p0 += __shfl_xor(p0, 2); p1 += __shfl_xor(p1, 2);
    p0 += __shfl_xor(p0, 4); p1 += __shfl_xor(p1, 4);
    if (j + 1 >= cnt) p1 = -INFINITY;

    float pm = fmaxf(p0, p1);
    if (__any(pm > m + 8.f)){
      float mn = fmaxf(m, pm);
      float sc = __expf(m - mn);
      s *= sc;
      ac4.x *= sc; ac4.y *= sc; ac4.z *= sc; ac4.w *= sc; acs *= sc;
      m = mn;
    }
    float w0 = __expf(p0 - m);
    float w1 = __expf(p1 - m);
    s += w0 + w1;
    ac4.x += w0*v40.x + w1*v41.x;
    ac4.y += w0*v40.y + w1*v41.y;
    ac4.z += w0*v40.z + w1*v41.z;
    ac4.w += w0*v40.w + w1*v41.w;
    acs   += w0*vs0   + w1*vs1;
  }

  float inv = 1.f/(s + 1e-16f);
  float o0 = ac4.x*inv, o1 = ac4.y*inv, o2 = ac4.z*inv, o3 = ac4.w*inv, o4 = acs*inv;
  // head mean: sum the 4 head groups (xor 8, 16 stay within the 32-lane half)
  o0 += __shfl_xor(o0, 8); o0 += __shfl_xor(o0, 16);
  o1 += __shfl_xor(o1, 8); o1 += __shfl_xor(o1, 16);
  o2 += __shfl_xor(o2, 8); o2 += __shfl_xor(o2, 16);
  o3 += __shfl_xor(o3, 8); o3 += __shfl_xor(o3, 16);
  o4 += __shfl_xor(o4, 8); o4 += __shfl_xor(o4, 16);
  if (h == 0){
    float4 b4 = *(const float4*)(bias + li*4);
    float4 r = make_float4(0.25f*o0 + b4.x, 0.25f*o1 + b4.y,
                           0.25f*o2 + b4.z, 0.25f*o3 + b4.w);
    *(float4*)(out + (size_t)node*OUTD + li*4) = r;
    out[(size_t)node*OUTD + 32 + li] = 0.25f*o4 + bias[32 + li];
  }
}

// ======================= launch =======================

extern "C" void kernel_launch(void* const* d_in, const int* in_sizes, int n_in,
                              void* d_out, int out_size, void* d_ws, size_t ws_size,
                              hipStream_t stream)
{
  const float* x     = (const float*)d_in[0];
  const int*   ei    = (const int*)  d_in[1];
  const float* Wl1   = (const float*)d_in[2];
  const float* bl1   = (const float*)d_in[3];
  const float* Wr1   = (const float*)d_in[4];
  const float* br1   = (const float*)d_in[5];
  const float* att1  = (const float*)d_in[6];
  const float* bias1 = (const float*)d_in[7];
  const float* Wl2   = (const float*)d_in[8];
  const float* bl2   = (const float*)d_in[9];
  const float* Wr2   = (const float*)d_in[10];
  const float* br2   = (const float*)d_in[11];
  const float* att2  = (const float*)d_in[12];
  const float* bias2 = (const float*)d_in[13];
  float* out = (float*)d_out;

  char* w = (char*)d_ws;
  size_t off = 0;
  auto alloc = [&](size_t bytes) -> void* {
    void* p = w + off;
    off = (off + bytes + 255) & ~(size_t)255;
    return p;
  };

  int* deg    = (int*)alloc((size_t)NNODES*4);
  int* rowptr = (int*)alloc((size_t)NNODES*4);
  int* pos    = (int*)alloc((size_t)NNODES*4);
  int* bsum   = (int*)alloc(256*4);
  int* boff   = (int*)alloc(256*4);
  int* csr    = (int*)alloc((size_t)ET*4);
  float* slabA = (float*)alloc((size_t)NNODES*160*4);  // xl1 then xl2
  float* slabB = (float*)alloc((size_t)NNODES*160*4);  // xr1 then xr2
  unsigned short* Xh = (unsigned short*)alloc((size_t)NNODES*256*2);  // later Hh
  unsigned short* Xl = (unsigned short*)alloc((size_t)NNODES*256*2);  // later Hl
  unsigned short* W1th = (unsigned short*)alloc((size_t)256*256*2);
  unsigned short* W1tl = (unsigned short*)alloc((size_t)256*256*2);
  unsigned short* W2th = (unsigned short*)alloc((size_t)320*128*2);
  unsigned short* W2tl = (unsigned short*)alloc((size_t)320*128*2);
  unsigned short* Hh = Xh;   // reuse: X splits dead after gemm1
  unsigned short* Hl = Xl;

  const int NB = (NNODES + 255)/256;         // 196
  const int EB = (ET + 255)/256;             // 3321

  // CSR
  hipMemsetAsync(deg, 0, (size_t)NNODES*4, stream);
  k_count<<<EB, 256, 0, stream>>>(ei, deg);
  k_bsum <<<NB, 256, 0, stream>>>(deg, bsum);
  k_scanb<<<1, 256, 0, stream>>>(bsum, NB, boff);
  k_scanw<<<NB, 256, 0, stream>>>(deg, boff, rowptr);
  hipMemcpyAsync(pos, rowptr, (size_t)NNODES*4, hipMemcpyDeviceToDevice, stream);
  k_scatter<<<EB, 256, 0, stream>>>(ei, pos, csr);

  // splits
  k_split_x<<<(NNODES*256/8 + 255)/256, 256, 0, stream>>>(x, Xh, Xl, NNODES*256/8);
  k_split_wt<<<(256*32 + 255)/256, 256, 0, stream>>>(Wl1, Wr1, 128, 256, 256, W1th, W1tl);
  k_split_wt<<<(320*16 + 255)/256, 256, 0, stream>>>(Wl2, Wr2, 160, 128, 320, W2th, W2tl);

  // layer 1
  dim3 g1((NNODES + 127)/128, 2);   // N=256
  k_gemm_mfma<<<g1, 256, 0, stream>>>(Xh, Xl, 256, NNODES,
                                      W1th, W1tl, 256, 128,
                                      bl1, br1, slabA, slabB, 128);
  k_agg1<<<6250, 256, 0, stream>>>(slabA, slabB, rowptr, deg, csr, att1, bias1, Hh, Hl);

  // layer 2
  dim3 g2((NNODES + 127)/128, 3);   // N=320 (last block half-masked)
  k_gemm_mfma<<<g2, 256, 0, stream>>>(Hh, Hl, 128, NNODES,
                                      W2th, W2tl, 320, 160,
                                      bl2, br2, slabA, slabB, 160);
  k_agg2<<<NNODES/8, 256, 0, stream>>>(slabA, slabB, rowptr, deg, csr, att2, bias2, out);
}

// Round 7
// 396.995 us; speedup vs baseline: 1.5246x; 1.1301x over previous
//
#include <hip/hip_runtime.h>
#include <math.h>

#define NNODES 50000
#define NEDGES 800000
#define ET (NNODES + NEDGES)   // 850000 with self loops
#define SLOPE 0.2f
#define OUTD 40

typedef __attribute__((ext_vector_type(8))) short short8;
typedef __attribute__((ext_vector_type(4))) float f32x4;

// float -> bf16 bits, round-to-nearest-even
__device__ inline unsigned short f2bf(float f){
  unsigned u = __float_as_uint(f);
  unsigned r = (u + 0x7FFFu + ((u >> 16) & 1u)) >> 16;
  return (unsigned short)r;
}
__device__ inline float bf2f(unsigned short h){
  return __uint_as_float(((unsigned)h) << 16);
}

// ======================= CSR build =======================

__global__ void k_count(const int* __restrict__ ei, int* __restrict__ deg){
  int e = blockIdx.x*256 + threadIdx.x;
  if (e >= ET) return;
  int dst = (e < NEDGES) ? ei[NEDGES + e] : (e - NEDGES);
  atomicAdd(&deg[dst], 1);
}

__global__ void k_bsum(const int* __restrict__ deg, int* __restrict__ bsum){
  int i = blockIdx.x*256 + threadIdx.x;
  int v = (i < NNODES) ? deg[i] : 0;
  for (int o = 1; o < 64; o <<= 1) v += __shfl_xor(v, o);
  __shared__ int ws[4];
  if ((threadIdx.x & 63) == 0) ws[threadIdx.x >> 6] = v;
  __syncthreads();
  if (threadIdx.x == 0) bsum[blockIdx.x] = ws[0] + ws[1] + ws[2] + ws[3];
}

__global__ void k_scanb(const int* __restrict__ bsum, int nb, int* __restrict__ boff){
  __shared__ int sm[256];
  int t = threadIdx.x;
  int v = (t < nb) ? bsum[t] : 0;
  sm[t] = v; __syncthreads();
  for (int d = 1; d < 256; d <<= 1){
    int x = (t >= d) ? sm[t - d] : 0;
    __syncthreads();
    sm[t] += x;
    __syncthreads();
  }
  if (t < nb) boff[t] = sm[t] - v;   // exclusive
}

__global__ void k_scanw(const int* __restrict__ deg, const int* __restrict__ boff,
                        int* __restrict__ rowptr){
  __shared__ int sm[256];
  int t = threadIdx.x, i = blockIdx.x*256 + t;
  int v = (i < NNODES) ? deg[i] : 0;
  sm[t] = v; __syncthreads();
  for (int d = 1; d < 256; d <<= 1){
    int x = (t >= d) ? sm[t - d] : 0;
    __syncthreads();
    sm[t] += x;
    __syncthreads();
  }
  if (i < NNODES) rowptr[i] = boff[blockIdx.x] + sm[t] - v;  // exclusive
}

__global__ void k_scatter(const int* __restrict__ ei, int* __restrict__ pos,
                          int* __restrict__ csr_src){
  int e = blockIdx.x*256 + threadIdx.x;
  if (e >= ET) return;
  int src, dst;
  if (e < NEDGES){ src = ei[e]; dst = ei[NEDGES + e]; }
  else           { src = dst = e - NEDGES; }
  int p = atomicAdd(&pos[dst], 1);
  csr_src[p] = src;
}

// ======================= split kernels (f32 -> bf16 hi/lo) ===================

__global__ void k_split_x(const float* __restrict__ x,
                          unsigned short* __restrict__ xh,
                          unsigned short* __restrict__ xl, int total8){
  int idx = blockIdx.x*256 + threadIdx.x;
  if (idx >= total8) return;
  const float4* p = (const float4*)x + (size_t)idx*2;
  float4 f0 = p[0], f1 = p[1];
  float f[8] = {f0.x,f0.y,f0.z,f0.w,f1.x,f1.y,f1.z,f1.w};
  unsigned h[8], lo[8];
  #pragma unroll
  for (int j = 0; j < 8; ++j){
    h[j] = f2bf(f[j]);
    lo[j] = f2bf(f[j] - bf2f((unsigned short)h[j]));
  }
  uint4 hv = make_uint4(h[0]|(h[1]<<16), h[2]|(h[3]<<16), h[4]|(h[5]<<16), h[6]|(h[7]<<16));
  uint4 lv = make_uint4(lo[0]|(lo[1]<<16), lo[2]|(lo[3]<<16), lo[4]|(lo[5]<<16), lo[6]|(lo[7]<<16));
  *(uint4*)(xh + (size_t)idx*8) = hv;
  *(uint4*)(xl + (size_t)idx*8) = lv;
}

__global__ void k_split_wt(const float* __restrict__ W0, const float* __restrict__ W1,
                           int split, int K, int Nf,
                           unsigned short* __restrict__ th,
                           unsigned short* __restrict__ tl){
  int kg8 = K >> 3;
  int idx = blockIdx.x*256 + threadIdx.x;
  if (idx >= Nf*kg8) return;
  int n  = idx / kg8;
  int kg = (idx - n*kg8) * 8;
  const float* src; int ld;
  if (n < split){ src = W0 + n;          ld = split; }
  else          { src = W1 + (n - split); ld = Nf - split; }
  unsigned h[8], lo[8];
  #pragma unroll
  for (int j = 0; j < 8; ++j){
    float v = src[(size_t)(kg + j) * ld];
    h[j]  = f2bf(v);
    lo[j] = f2bf(v - bf2f((unsigned short)h[j]));
  }
  uint4 hv = make_uint4(h[0]|(h[1]<<16), h[2]|(h[3]<<16), h[4]|(h[5]<<16), h[6]|(h[7]<<16));
  uint4 lv = make_uint4(lo[0]|(lo[1]<<16), lo[2]|(lo[3]<<16), lo[4]|(lo[5]<<16), lo[6]|(lo[7]<<16));
  *(uint4*)(th + (size_t)n*K + kg) = hv;
  *(uint4*)(tl + (size_t)n*K + kg) = lv;
}

// ======================= MFMA GEMM (split-bf16 x3) ==========================
// O columns < split (the xl transform) are stored as BF16 rows (gather side);
// columns >= split (xr transform) stored f32.

__global__ __launch_bounds__(256) void k_gemm_mfma(
    const unsigned short* __restrict__ Xh, const unsigned short* __restrict__ Xl,
    int Kd, int M,
    const unsigned short* __restrict__ Wth, const unsigned short* __restrict__ Wtl,
    int Nf, int split,
    const float* __restrict__ b0, const float* __restrict__ b1,
    unsigned short* __restrict__ O0b, float* __restrict__ O1, int ldO)
{
  __shared__ unsigned short ldsA[128*64];
  __shared__ unsigned short ldsB[128*64];
  char* cA = (char*)ldsA;
  char* cB = (char*)ldsB;

  int t = threadIdx.x;
  int w = t >> 6, l = t & 63;
  int wr = w >> 1, wc = w & 1;
  int lr = l & 15, lg = l >> 4;

  int row0 = blockIdx.x * 128;
  int col0 = blockIdx.y * 128;

  f32x4 acc[4][4];
  #pragma unroll
  for (int i = 0; i < 4; ++i)
    #pragma unroll
    for (int j = 0; j < 4; ++j) acc[i][j] = (f32x4){0.f,0.f,0.f,0.f};

  int sr_off = l >> 3;
  int slot   = 0;

  for (int k0 = 0; k0 < Kd; k0 += 32){
    __syncthreads();
    #pragma unroll
    for (int i = 0; i < 4; ++i){
      int chunk = w*4 + i;
      int r = chunk*8 + sr_off;
      slot = (l & 7) ^ (r & 7);
      int h = slot >> 2, g = slot & 3;
      int row = row0 + r; if (row > M-1) row = M-1;
      const unsigned short* src = (h ? Xl : Xh) + (size_t)row*Kd + k0 + g*8;
      __builtin_amdgcn_global_load_lds(
          (const __attribute__((address_space(1))) void*)src,
          (__attribute__((address_space(3))) void*)(cA + chunk*1024), 16, 0, 0);
    }
    #pragma unroll
    for (int i = 0; i < 4; ++i){
      int chunk = w*4 + i;
      int r = chunk*8 + sr_off;
      slot = (l & 7) ^ (r & 7);
      int h = slot >> 2, g = slot & 3;
      int n = col0 + r; if (n > Nf-1) n = Nf-1;
      const unsigned short* src = (h ? Wtl : Wth) + (size_t)n*Kd + k0 + g*8;
      __builtin_amdgcn_global_load_lds(
          (const __attribute__((address_space(1))) void*)src,
          (__attribute__((address_space(3))) void*)(cB + chunk*1024), 16, 0, 0);
    }
    __syncthreads();

    short8 ah[4], al[4], bh[4], bl[4];
    #pragma unroll
    for (int mi = 0; mi < 4; ++mi){
      int r = wr*64 + mi*16 + lr;
      unsigned sw = (unsigned)((r & 7) << 4);
      unsigned ba = (unsigned)(r*128 + lg*16);
      ah[mi] = *(const short8*)(cA + (ba ^ sw));
      al[mi] = *(const short8*)(cA + ((ba + 64) ^ sw));
    }
    #pragma unroll
    for (int ni = 0; ni < 4; ++ni){
      int n = wc*64 + ni*16 + lr;
      unsigned sw = (unsigned)((n & 7) << 4);
      unsigned bb = (unsigned)(n*128 + lg*16);
      bh[ni] = *(const short8*)(cB + (bb ^ sw));
      bl[ni] = *(const short8*)(cB + ((bb + 64) ^ sw));
    }
    #pragma unroll
    for (int mi = 0; mi < 4; ++mi)
      #pragma unroll
      for (int ni = 0; ni < 4; ++ni){
        acc[mi][ni] = __builtin_amdgcn_mfma_f32_16x16x32_bf16(ah[mi], bh[ni], acc[mi][ni], 0, 0, 0);
        acc[mi][ni] = __builtin_amdgcn_mfma_f32_16x16x32_bf16(ah[mi], bl[ni], acc[mi][ni], 0, 0, 0);
        acc[mi][ni] = __builtin_amdgcn_mfma_f32_16x16x32_bf16(al[mi], bh[ni], acc[mi][ni], 0, 0, 0);
      }
  }

  #pragma unroll
  for (int ni = 0; ni < 4; ++ni){
    int col = col0 + wc*64 + ni*16 + lr;
    if (col >= Nf) continue;
    if (col < split){
      float bias = b0[col];
      unsigned short* O = O0b + col;
      #pragma unroll
      for (int mi = 0; mi < 4; ++mi){
        int rbase = row0 + wr*64 + mi*16 + lg*4;
        #pragma unroll
        for (int q = 0; q < 4; ++q){
          int row = rbase + q;
          if (row < M) O[(size_t)row * ldO] = f2bf(acc[mi][ni][q] + bias);
        }
      }
    } else {
      float bias = b1[col - split];
      float* O = O1 + (col - split);
      #pragma unroll
      for (int mi = 0; mi < 4; ++mi){
        int rbase = row0 + wr*64 + mi*16 + lg*4;
        #pragma unroll
        for (int q = 0; q < 4; ++q){
          int row = rbase + q;
          if (row < M) O[(size_t)row * ldO] = acc[mi][ni][q] + bias;
        }
      }
    }
  }
}

// ======================= Layer 1 aggregation (fused softmax) =================
// 32 lanes/node (2 nodes/wave). Gathered xl rows are BF16 (256 B/row). Lane
// (h,li) owns channels h*32+4*li..+3 (uint2 -> 4 bf16). xr stays f32. Edge-pair
// loop, 2-edge lookahead, branch-free tail (p1=-inf), defer-max softmax.
__global__ __launch_bounds__(256) void k_agg1(
    const unsigned short* __restrict__ xlb, const float* __restrict__ xr,
    const int* __restrict__ rowptr, const int* __restrict__ deg,
    const int* __restrict__ csr, const float* __restrict__ att,
    const float* __restrict__ bias,
    unsigned short* __restrict__ Hh, unsigned short* __restrict__ Hl)
{
  int node = blockIdx.x*8 + (threadIdx.x >> 5);
  int l  = threadIdx.x & 31;
  int h  = l >> 3;
  int li = l & 7;
  int c0 = h*32 + li*4;

  float4 av  = *(const float4*)(att + c0);
  float4 xrv = *(const float4*)(xr + (size_t)node*128 + c0);

  int start = rowptr[node], cnt = deg[node];
  int last = cnt - 1;

  int i0 = csr[start];
  int i1 = csr[start + min(1, last)];
  uint2 r0 = *(const uint2*)(xlb + (size_t)i0*128 + c0);
  uint2 r1 = *(const uint2*)(xlb + (size_t)i1*128 + c0);
  int ia = csr[start + min(2, last)];
  int ib = csr[start + min(3, last)];

  float m = -INFINITY, s = 0.f;
  float4 acc = make_float4(0.f, 0.f, 0.f, 0.f);

  for (int j = 0; j < cnt; j += 2){
    uint2 u0 = r0, u1 = r1;
    r0 = *(const uint2*)(xlb + (size_t)ia*128 + c0);
    r1 = *(const uint2*)(xlb + (size_t)ib*128 + c0);
    ia = csr[start + min(j + 4, last)];
    ib = csr[start + min(j + 5, last)];

    float v00 = bf2f((unsigned short)u0.x), v01 = bf2f((unsigned short)(u0.x >> 16));
    float v02 = bf2f((unsigned short)u0.y), v03 = bf2f((unsigned short)(u0.y >> 16));
    float v10 = bf2f((unsigned short)u1.x), v11 = bf2f((unsigned short)(u1.x >> 16));
    float v12 = bf2f((unsigned short)u1.y), v13 = bf2f((unsigned short)(u1.y >> 16));

    float g0, g1, g2, g3;
    g0 = v00 + xrv.x; g0 = fmaxf(g0, SLOPE*g0);
    g1 = v01 + xrv.y; g1 = fmaxf(g1, SLOPE*g1);
    g2 = v02 + xrv.z; g2 = fmaxf(g2, SLOPE*g2);
    g3 = v03 + xrv.w; g3 = fmaxf(g3, SLOPE*g3);
    float p0 = g0*av.x + g1*av.y + g2*av.z + g3*av.w;
    g0 = v10 + xrv.x; g0 = fmaxf(g0, SLOPE*g0);
    g1 = v11 + xrv.y; g1 = fmaxf(g1, SLOPE*g1);
    g2 = v12 + xrv.z; g2 = fmaxf(g2, SLOPE*g2);
    g3 = v13 + xrv.w; g3 = fmaxf(g3, SLOPE*g3);
    float p1 = g0*av.x + g1*av.y + g2*av.z + g3*av.w;

    p0 += __shfl_xor(p0, 1); p1 += __shfl_xor(p1, 1);
    p0 += __shfl_xor(p0, 2); p1 += __shfl_xor(p1, 2);
    p0 += __shfl_xor(p0, 4); p1 += __shfl_xor(p1, 4);
    if (j + 1 >= cnt) p1 = -INFINITY;   // tail edge contributes weight 0

    float pm = fmaxf(p0, p1);
    if (__any(pm > m + 8.f)){           // defer-max: rescale rarely
      float mn = fmaxf(m, pm);
      float sc = __expf(m - mn);
      s *= sc;
      acc.x *= sc; acc.y *= sc; acc.z *= sc; acc.w *= sc;
      m = mn;
    }
    float w0 = __expf(p0 - m);
    float w1 = __expf(p1 - m);
    s += w0 + w1;
    acc.x += w0*v00 + w1*v10;
    acc.y += w0*v01 + w1*v11;
    acc.z += w0*v02 + w1*v12;
    acc.w += w0*v03 + w1*v13;
  }

  float inv = 1.f/(s + 1e-16f);
  float4 b4 = *(const float4*)(bias + c0);
  float o[4];
  o[0] = acc.x*inv + b4.x;
  o[1] = acc.y*inv + b4.y;
  o[2] = acc.z*inv + b4.z;
  o[3] = acc.w*inv + b4.w;
  unsigned hh[4], hlv[4];
  #pragma unroll
  for (int j = 0; j < 4; ++j){
    float e = o[j] > 0.f ? o[j] : (__expf(o[j]) - 1.f);   // ELU
    hh[j]  = f2bf(e);
    hlv[j] = f2bf(e - bf2f((unsigned short)hh[j]));
  }
  *(uint2*)(Hh + (size_t)node*128 + c0) = make_uint2(hh[0]|(hh[1]<<16), hh[2]|(hh[3]<<16));
  *(uint2*)(Hl + (size_t)node*128 + c0) = make_uint2(hlv[0]|(hlv[1]<<16), hlv[2]|(hlv[3]<<16));
}

// ======================= Layer 2 aggregation (head-mean) =====================
// 2 nodes/wave, 32 lanes/node. Gathered xl rows BF16 (320 B/row). Lane (h,li)
// owns uint2 (4 bf16) at h*40+li*4 plus bf16 scalar at h*40+32+li. xr f32.
__global__ __launch_bounds__(256) void k_agg2(
    const unsigned short* __restrict__ xlb, const float* __restrict__ xr,
    const int* __restrict__ rowptr, const int* __restrict__ deg,
    const int* __restrict__ csr, const float* __restrict__ att,
    const float* __restrict__ bias, float* __restrict__ out)
{
  int node = blockIdx.x*8 + (threadIdx.x >> 5);
  int hl   = threadIdx.x & 31;
  int h  = hl >> 3;
  int li = hl & 7;
  int c4 = h*40 + li*4;
  int cs = h*40 + 32 + li;

  float4 a4 = *(const float4*)(att + c4);
  float  as = att[cs];
  const float* xrp = xr + (size_t)node*160;
  float4 r4 = *(const float4*)(xrp + c4);
  float  rs = xrp[cs];

  int start = rowptr[node], cnt = deg[node];
  int last = cnt - 1;

  int i0 = csr[start];
  int i1 = csr[start + min(1, last)];
  uint2 rv0 = *(const uint2*)(xlb + (size_t)i0*160 + c4);
  unsigned short sv0 = xlb[(size_t)i0*160 + cs];
  uint2 rv1 = *(const uint2*)(xlb + (size_t)i1*160 + c4);
  unsigned short sv1 = xlb[(size_t)i1*160 + cs];
  int ia = csr[start + min(2, last)];
  int ib = csr[start + min(3, last)];

  float m = -INFINITY, s = 0.f;
  float4 ac4 = make_float4(0.f,0.f,0.f,0.f);
  float  acs = 0.f;

  for (int j = 0; j < cnt; j += 2){
    uint2 u0 = rv0, u1 = rv1;
    unsigned short t0 = sv0, t1 = sv1;
    rv0 = *(const uint2*)(xlb + (size_t)ia*160 + c4);
    sv0 = xlb[(size_t)ia*160 + cs];
    rv1 = *(const uint2*)(xlb + (size_t)ib*160 + c4);
    sv1 = xlb[(size_t)ib*160 + cs];
    ia = csr[start + min(j + 4, last)];
    ib = csr[start + min(j + 5, last)];

    float v00 = bf2f((unsigned short)u0.x), v01 = bf2f((unsigned short)(u0.x >> 16));
    float v02 = bf2f((unsigned short)u0.y), v03 = bf2f((unsigned short)(u0.y >> 16));
    float vs0 = bf2f(t0);
    float v10 = bf2f((unsigned short)u1.x), v11 = bf2f((unsigned short)(u1.x >> 16));
    float v12 = bf2f((unsigned short)u1.y), v13 = bf2f((unsigned short)(u1.y >> 16));
    float vs1 = bf2f(t1);

    float g0, g1, g2, g3, g4;
    g0 = v00 + r4.x; g0 = fmaxf(g0, SLOPE*g0);
    g1 = v01 + r4.y; g1 = fmaxf(g1, SLOPE*g1);
    g2 = v02 + r4.z; g2 = fmaxf(g2, SLOPE*g2);
    g3 = v03 + r4.w; g3 = fmaxf(g3, SLOPE*g3);
    g4 = vs0 + rs;   g4 = fmaxf(g4, SLOPE*g4);
    float p0 = g0*a4.x + g1*a4.y + g2*a4.z + g3*a4.w + g4*as;
    g0 = v10 + r4.x; g0 = fmaxf(g0, SLOPE*g0);
    g1 = v11 + r4.y; g1 = fmaxf(g1, SLOPE*g1);
    g2 = v12 + r4.z; g2 = fmaxf(g2, SLOPE*g2);
    g3 = v13 + r4.w; g3 = fmaxf(g3, SLOPE*g3);
    g4 = vs1 + rs;   g4 = fmaxf(g4, SLOPE*g4);
    float p1 = g0*a4.x + g1*a4.y + g2*a4.z + g3*a4.w + g4*as;

    p0 += __shfl_xor(p0, 1); p1 += __shfl_xor(p1, 1);
    p0 += __shfl_xor(p0, 2); p1 += __shfl_xor(p1, 2);
    p0 += __shfl_xor(p0, 4); p1 += __shfl_xor(p1, 4);
    if (j + 1 >= cnt) p1 = -INFINITY;

    float pm = fmaxf(p0, p1);
    if (__any(pm > m + 8.f)){
      float mn = fmaxf(m, pm);
      float sc = __expf(m - mn);
      s *= sc;
      ac4.x *= sc; ac4.y *= sc; ac4.z *= sc; ac4.w *= sc; acs *= sc;
      m = mn;
    }
    float w0 = __expf(p0 - m);
    float w1 = __expf(p1 - m);
    s += w0 + w1;
    ac4.x += w0*v00 + w1*v10;
    ac4.y += w0*v01 + w1*v11;
    ac4.z += w0*v02 + w1*v12;
    ac4.w += w0*v03 + w1*v13;
    acs   += w0*vs0 + w1*vs1;
  }

  float inv = 1.f/(s + 1e-16f);
  float o0 = ac4.x*inv, o1 = ac4.y*inv, o2 = ac4.z*inv, o3 = ac4.w*inv, o4 = acs*inv;
  // head mean: sum the 4 head groups (xor 8, 16 stay within the 32-lane half)
  o0 += __shfl_xor(o0, 8); o0 += __shfl_xor(o0, 16);
  o1 += __shfl_xor(o1, 8); o1 += __shfl_xor(o1, 16);
  o2 += __shfl_xor(o2, 8); o2 += __shfl_xor(o2, 16);
  o3 += __shfl_xor(o3, 8); o3 += __shfl_xor(o3, 16);
  o4 += __shfl_xor(o4, 8); o4 += __shfl_xor(o4, 16);
  if (h == 0){
    float4 b4 = *(const float4*)(bias + li*4);
    float4 r = make_float4(0.25f*o0 + b4.x, 0.25f*o1 + b4.y,
                           0.25f*o2 + b4.z, 0.25f*o3 + b4.w);
    *(float4*)(out + (size_t)node*OUTD + li*4) = r;
    out[(size_t)node*OUTD + 32 + li] = 0.25f*o4 + bias[32 + li];
  }
}

// ======================= launch =======================

extern "C" void kernel_launch(void* const* d_in, const int* in_sizes, int n_in,
                              void* d_out, int out_size, void* d_ws, size_t ws_size,
                              hipStream_t stream)
{
  const float* x     = (const float*)d_in[0];
  const int*   ei    = (const int*)  d_in[1];
  const float* Wl1   = (const float*)d_in[2];
  const float* bl1   = (const float*)d_in[3];
  const float* Wr1   = (const float*)d_in[4];
  const float* br1   = (const float*)d_in[5];
  const float* att1  = (const float*)d_in[6];
  const float* bias1 = (const float*)d_in[7];
  const float* Wl2   = (const float*)d_in[8];
  const float* bl2   = (const float*)d_in[9];
  const float* Wr2   = (const float*)d_in[10];
  const float* br2   = (const float*)d_in[11];
  const float* att2  = (const float*)d_in[12];
  const float* bias2 = (const float*)d_in[13];
  float* out = (float*)d_out;

  char* w = (char*)d_ws;
  size_t off = 0;
  auto alloc = [&](size_t bytes) -> void* {
    void* p = w + off;
    off = (off + bytes + 255) & ~(size_t)255;
    return p;
  };

  int* deg    = (int*)alloc((size_t)NNODES*4);
  int* rowptr = (int*)alloc((size_t)NNODES*4);
  int* pos    = (int*)alloc((size_t)NNODES*4);
  int* bsum   = (int*)alloc(256*4);
  int* boff   = (int*)alloc(256*4);
  int* csr    = (int*)alloc((size_t)ET*4);
  unsigned short* xlbuf = (unsigned short*)alloc((size_t)NNODES*160*2); // bf16 xl rows (l1: ld128, l2: ld160)
  float* xrbuf = (float*)alloc((size_t)NNODES*160*4);                   // f32 xr rows
  unsigned short* Xh = (unsigned short*)alloc((size_t)NNODES*256*2);    // later Hh
  unsigned short* Xl = (unsigned short*)alloc((size_t)NNODES*256*2);    // later Hl
  unsigned short* W1th = (unsigned short*)alloc((size_t)256*256*2);
  unsigned short* W1tl = (unsigned short*)alloc((size_t)256*256*2);
  unsigned short* W2th = (unsigned short*)alloc((size_t)320*128*2);
  unsigned short* W2tl = (unsigned short*)alloc((size_t)320*128*2);
  unsigned short* Hh = Xh;   // reuse: X splits dead after gemm1
  unsigned short* Hl = Xl;

  const int NB = (NNODES + 255)/256;         // 196
  const int EB = (ET + 255)/256;             // 3321

  // CSR
  hipMemsetAsync(deg, 0, (size_t)NNODES*4, stream);
  k_count<<<EB, 256, 0, stream>>>(ei, deg);
  k_bsum <<<NB, 256, 0, stream>>>(deg, bsum);
  k_scanb<<<1, 256, 0, stream>>>(bsum, NB, boff);
  k_scanw<<<NB, 256, 0, stream>>>(deg, boff, rowptr);
  hipMemcpyAsync(pos, rowptr, (size_t)NNODES*4, hipMemcpyDeviceToDevice, stream);
  k_scatter<<<EB, 256, 0, stream>>>(ei, pos, csr);

  // splits
  k_split_x<<<(NNODES*256/8 + 255)/256, 256, 0, stream>>>(x, Xh, Xl, NNODES*256/8);
  k_split_wt<<<(256*32 + 255)/256, 256, 0, stream>>>(Wl1, Wr1, 128, 256, 256, W1th, W1tl);
  k_split_wt<<<(320*16 + 255)/256, 256, 0, stream>>>(Wl2, Wr2, 160, 128, 320, W2th, W2tl);

  // layer 1
  dim3 g1((NNODES + 127)/128, 2);   // N=256
  k_gemm_mfma<<<g1, 256, 0, stream>>>(Xh, Xl, 256, NNODES,
                                      W1th, W1tl, 256, 128,
                                      bl1, br1, xlbuf, xrbuf, 128);
  k_agg1<<<6250, 256, 0, stream>>>(xlbuf, xrbuf, rowptr, deg, csr, att1, bias1, Hh, Hl);

  // layer 2
  dim3 g2((NNODES + 127)/128, 3);   // N=320 (last block half-masked)
  k_gemm_mfma<<<g2, 256, 0, stream>>>(Hh, Hl, 128, NNODES,
                                      W2th, W2tl, 320, 160,
                                      bl2, br2, xlbuf, xrbuf, 160);
  k_agg2<<<NNODES/8, 256, 0, stream>>>(xlbuf, xrbuf, rowptr, deg, csr, att2, bias2, out);
}

// Round 10
// 339.682 us; speedup vs baseline: 1.7819x; 1.1687x over previous
//
#include <hip/hip_runtime.h>
#include <math.h>

#define NNODES 50000
#define NEDGES 800000
#define ET (NNODES + NEDGES)   // 850000 with self loops
#define SLOPE 0.2f
#define OUTD 40

// bucket partition for CSR build
#define BW_SH 7
#define NBUCK 391              // ceil(50000/128)
#define BCAP 4096              // mean 2176, sigma ~47 -> huge margin

typedef __attribute__((ext_vector_type(8))) short short8;
typedef __attribute__((ext_vector_type(4))) float f32x4;

// float -> bf16 bits, round-to-nearest-even
__device__ inline unsigned short f2bf(float f){
  unsigned u = __float_as_uint(f);
  unsigned r = (u + 0x7FFFu + ((u >> 16) & 1u)) >> 16;
  return (unsigned short)r;
}
__device__ inline float bf2f(unsigned short h){
  return __uint_as_float(((unsigned)h) << 16);
}

// ======================= CSR build (bucketed) =======================

// Pass A: partition edges into 391 dst-range buckets. One global atomic per
// block per bucket (LDS histogram); pair writes are short contiguous runs.
__global__ __launch_bounds__(256) void k_part(const int* __restrict__ ei,
                                              int* __restrict__ bcount,
                                              uint2* __restrict__ pairs){
  __shared__ int hist[NBUCK];
  __shared__ int curp[NBUCK];
  int t = threadIdx.x;
  const int EPB = (ET + 255) / 256;            // edges per block (chunked)
  int start = blockIdx.x * EPB;
  int end = min(start + EPB, ET);

  for (int b = t; b < NBUCK; b += 256) hist[b] = 0;
  __syncthreads();
  for (int e = start + t; e < end; e += 256){
    int dst = (e < NEDGES) ? ei[NEDGES + e] : (e - NEDGES);
    atomicAdd(&hist[dst >> BW_SH], 1);
  }
  __syncthreads();
  for (int b = t; b < NBUCK; b += 256){
    int c = hist[b];
    curp[b] = (c > 0) ? atomicAdd(&bcount[b], c) : 0;
  }
  __syncthreads();
  for (int e = start + t; e < end; e += 256){
    int src, dst;
    if (e < NEDGES){ src = ei[e]; dst = ei[NEDGES + e]; }
    else           { src = dst = e - NEDGES; }
    int b = dst >> BW_SH;
    int p = atomicAdd(&curp[b], 1);
    pairs[(size_t)b*BCAP + p] = make_uint2((unsigned)src, (unsigned)dst);
  }
}

// Pass B: per-bucket degree count in LDS, coalesced store.
__global__ __launch_bounds__(256) void k_bdeg(const int* __restrict__ bcount,
                                              const uint2* __restrict__ pairs,
                                              int* __restrict__ deg){
  __shared__ int ldeg[128];
  int b = blockIdx.x, t = threadIdx.x;
  if (t < 128) ldeg[t] = 0;
  __syncthreads();
  int n = bcount[b];
  const uint2* pp = pairs + (size_t)b*BCAP;
  for (int i = t; i < n; i += 256)
    atomicAdd(&ldeg[(int)pp[i].y & 127], 1);
  __syncthreads();
  int base = b << BW_SH;
  if (t < 128 && base + t < NNODES) deg[base + t] = ldeg[t];
}

// Pass C: place edges; csr writes confined to this bucket's ~9KB region.
__global__ __launch_bounds__(256) void k_bscatter(const int* __restrict__ bcount,
                                                  const uint2* __restrict__ pairs,
                                                  const int* __restrict__ rowptr,
                                                  int* __restrict__ csr){
  __shared__ int lpos[128];
  int b = blockIdx.x, t = threadIdx.x;
  int base = b << BW_SH;
  if (t < 128 && base + t < NNODES) lpos[t] = rowptr[base + t];
  __syncthreads();
  int n = bcount[b];
  const uint2* pp = pairs + (size_t)b*BCAP;
  for (int i = t; i < n; i += 256){
    uint2 e = pp[i];
    int p = atomicAdd(&lpos[(int)e.y & 127], 1);
    csr[p] = (int)e.x;
  }
}

__global__ void k_bsum(const int* __restrict__ deg, int* __restrict__ bsum){
  int i = blockIdx.x*256 + threadIdx.x;
  int v = (i < NNODES) ? deg[i] : 0;
  for (int o = 1; o < 64; o <<= 1) v += __shfl_xor(v, o);
  __shared__ int ws[4];
  if ((threadIdx.x & 63) == 0) ws[threadIdx.x >> 6] = v;
  __syncthreads();
  if (threadIdx.x == 0) bsum[blockIdx.x] = ws[0] + ws[1] + ws[2] + ws[3];
}

__global__ void k_scanb(const int* __restrict__ bsum, int nb, int* __restrict__ boff){
  __shared__ int sm[256];
  int t = threadIdx.x;
  int v = (t < nb) ? bsum[t] : 0;
  sm[t] = v; __syncthreads();
  for (int d = 1; d < 256; d <<= 1){
    int x = (t >= d) ? sm[t - d] : 0;
    __syncthreads();
    sm[t] += x;
    __syncthreads();
  }
  if (t < nb) boff[t] = sm[t] - v;   // exclusive
}

__global__ void k_scanw(const int* __restrict__ deg, const int* __restrict__ boff,
                        int* __restrict__ rowptr){
  __shared__ int sm[256];
  int t = threadIdx.x, i = blockIdx.x*256 + t;
  int v = (i < NNODES) ? deg[i] : 0;
  sm[t] = v; __syncthreads();
  for (int d = 1; d < 256; d <<= 1){
    int x = (t >= d) ? sm[t - d] : 0;
    __syncthreads();
    sm[t] += x;
    __syncthreads();
  }
  if (i < NNODES) rowptr[i] = boff[blockIdx.x] + sm[t] - v;  // exclusive
}

// ======================= split kernels (f32 -> bf16 hi/lo) ===================

__global__ void k_split_x(const float* __restrict__ x,
                          unsigned short* __restrict__ xh,
                          unsigned short* __restrict__ xl, int total8){
  int idx = blockIdx.x*256 + threadIdx.x;
  if (idx >= total8) return;
  const float4* p = (const float4*)x + (size_t)idx*2;
  float4 f0 = p[0], f1 = p[1];
  float f[8] = {f0.x,f0.y,f0.z,f0.w,f1.x,f1.y,f1.z,f1.w};
  unsigned h[8], lo[8];
  #pragma unroll
  for (int j = 0; j < 8; ++j){
    h[j] = f2bf(f[j]);
    lo[j] = f2bf(f[j] - bf2f((unsigned short)h[j]));
  }
  uint4 hv = make_uint4(h[0]|(h[1]<<16), h[2]|(h[3]<<16), h[4]|(h[5]<<16), h[6]|(h[7]<<16));
  uint4 lv = make_uint4(lo[0]|(lo[1]<<16), lo[2]|(lo[3]<<16), lo[4]|(lo[5]<<16), lo[6]|(lo[7]<<16));
  *(uint4*)(xh + (size_t)idx*8) = hv;
  *(uint4*)(xl + (size_t)idx*8) = lv;
}

__global__ void k_split_wt(const float* __restrict__ W0, const float* __restrict__ W1,
                           int split, int K, int Nf,
                           unsigned short* __restrict__ th,
                           unsigned short* __restrict__ tl){
  int kg8 = K >> 3;
  int idx = blockIdx.x*256 + threadIdx.x;
  if (idx >= Nf*kg8) return;
  int n  = idx / kg8;
  int kg = (idx - n*kg8) * 8;
  const float* src; int ld;
  if (n < split){ src = W0 + n;          ld = split; }
  else          { src = W1 + (n - split); ld = Nf - split; }
  unsigned h[8], lo[8];
  #pragma unroll
  for (int j = 0; j < 8; ++j){
    float v = src[(size_t)(kg + j) * ld];
    h[j]  = f2bf(v);
    lo[j] = f2bf(v - bf2f((unsigned short)h[j]));
  }
  uint4 hv = make_uint4(h[0]|(h[1]<<16), h[2]|(h[3]<<16), h[4]|(h[5]<<16), h[6]|(h[7]<<16));
  uint4 lv = make_uint4(lo[0]|(lo[1]<<16), lo[2]|(lo[3]<<16), lo[4]|(lo[5]<<16), lo[6]|(lo[7]<<16));
  *(uint4*)(th + (size_t)n*K + kg) = hv;
  *(uint4*)(tl + (size_t)n*K + kg) = lv;
}

// ======================= MFMA GEMM (split-bf16 x3) ==========================
// O columns < split (the xl transform) are stored as BF16 rows (gather side);
// columns >= split (xr transform) stored f32.

__global__ __launch_bounds__(256) void k_gemm_mfma(
    const unsigned short* __restrict__ Xh, const unsigned short* __restrict__ Xl,
    int Kd, int M,
    const unsigned short* __restrict__ Wth, const unsigned short* __restrict__ Wtl,
    int Nf, int split,
    const float* __restrict__ b0, const float* __restrict__ b1,
    unsigned short* __restrict__ O0b, float* __restrict__ O1, int ldO)
{
  __shared__ unsigned short ldsA[128*64];
  __shared__ unsigned short ldsB[128*64];
  char* cA = (char*)ldsA;
  char* cB = (char*)ldsB;

  int t = threadIdx.x;
  int w = t >> 6, l = t & 63;
  int wr = w >> 1, wc = w & 1;
  int lr = l & 15, lg = l >> 4;

  int row0 = blockIdx.x * 128;
  int col0 = blockIdx.y * 128;

  f32x4 acc[4][4];
  #pragma unroll
  for (int i = 0; i < 4; ++i)
    #pragma unroll
    for (int j = 0; j < 4; ++j) acc[i][j] = (f32x4){0.f,0.f,0.f,0.f};

  int sr_off = l >> 3;
  int slot   = 0;

  for (int k0 = 0; k0 < Kd; k0 += 32){
    __syncthreads();
    #pragma unroll
    for (int i = 0; i < 4; ++i){
      int chunk = w*4 + i;
      int r = chunk*8 + sr_off;
      slot = (l & 7) ^ (r & 7);
      int h = slot >> 2, g = slot & 3;
      int row = row0 + r; if (row > M-1) row = M-1;
      const unsigned short* src = (h ? Xl : Xh) + (size_t)row*Kd + k0 + g*8;
      __builtin_amdgcn_global_load_lds(
          (const __attribute__((address_space(1))) void*)src,
          (__attribute__((address_space(3))) void*)(cA + chunk*1024), 16, 0, 0);
    }
    #pragma unroll
    for (int i = 0; i < 4; ++i){
      int chunk = w*4 + i;
      int r = chunk*8 + sr_off;
      slot = (l & 7) ^ (r & 7);
      int h = slot >> 2, g = slot & 3;
      int n = col0 + r; if (n > Nf-1) n = Nf-1;
      const unsigned short* src = (h ? Wtl : Wth) + (size_t)n*Kd + k0 + g*8;
      __builtin_amdgcn_global_load_lds(
          (const __attribute__((address_space(1))) void*)src,
          (__attribute__((address_space(3))) void*)(cB + chunk*1024), 16, 0, 0);
    }
    __syncthreads();

    short8 ah[4], al[4], bh[4], bl[4];
    #pragma unroll
    for (int mi = 0; mi < 4; ++mi){
      int r = wr*64 + mi*16 + lr;
      unsigned sw = (unsigned)((r & 7) << 4);
      unsigned ba = (unsigned)(r*128 + lg*16);
      ah[mi] = *(const short8*)(cA + (ba ^ sw));
      al[mi] = *(const short8*)(cA + ((ba + 64) ^ sw));
    }
    #pragma unroll
    for (int ni = 0; ni < 4; ++ni){
      int n = wc*64 + ni*16 + lr;
      unsigned sw = (unsigned)((n & 7) << 4);
      unsigned bb = (unsigned)(n*128 + lg*16);
      bh[ni] = *(const short8*)(cB + (bb ^ sw));
      bl[ni] = *(const short8*)(cB + ((bb + 64) ^ sw));
    }
    #pragma unroll
    for (int mi = 0; mi < 4; ++mi)
      #pragma unroll
      for (int ni = 0; ni < 4; ++ni){
        acc[mi][ni] = __builtin_amdgcn_mfma_f32_16x16x32_bf16(ah[mi], bh[ni], acc[mi][ni], 0, 0, 0);
        acc[mi][ni] = __builtin_amdgcn_mfma_f32_16x16x32_bf16(ah[mi], bl[ni], acc[mi][ni], 0, 0, 0);
        acc[mi][ni] = __builtin_amdgcn_mfma_f32_16x16x32_bf16(al[mi], bh[ni], acc[mi][ni], 0, 0, 0);
      }
  }

  #pragma unroll
  for (int ni = 0; ni < 4; ++ni){
    int col = col0 + wc*64 + ni*16 + lr;
    if (col >= Nf) continue;
    if (col < split){
      float bias = b0[col];
      unsigned short* O = O0b + col;
      #pragma unroll
      for (int mi = 0; mi < 4; ++mi){
        int rbase = row0 + wr*64 + mi*16 + lg*4;
        #pragma unroll
        for (int q = 0; q < 4; ++q){
          int row = rbase + q;
          if (row < M) O[(size_t)row * ldO] = f2bf(acc[mi][ni][q] + bias);
        }
      }
    } else {
      float bias = b1[col - split];
      float* O = O1 + (col - split);
      #pragma unroll
      for (int mi = 0; mi < 4; ++mi){
        int rbase = row0 + wr*64 + mi*16 + lg*4;
        #pragma unroll
        for (int q = 0; q < 4; ++q){
          int row = rbase + q;
          if (row < M) O[(size_t)row * ldO] = acc[mi][ni][q] + bias;
        }
      }
    }
  }
}

// ======================= Layer 1 aggregation (fused softmax) =================
__global__ __launch_bounds__(256) void k_agg1(
    const unsigned short* __restrict__ xlb, const float* __restrict__ xr,
    const int* __restrict__ rowptr, const int* __restrict__ deg,
    const int* __restrict__ csr, const float* __restrict__ att,
    const float* __restrict__ bias,
    unsigned short* __restrict__ Hh, unsigned short* __restrict__ Hl)
{
  int node = blockIdx.x*8 + (threadIdx.x >> 5);
  int l  = threadIdx.x & 31;
  int h  = l >> 3;
  int li = l & 7;
  int c0 = h*32 + li*4;

  float4 av  = *(const float4*)(att + c0);
  float4 xrv = *(const float4*)(xr + (size_t)node*128 + c0);

  int start = rowptr[node], cnt = deg[node];
  int last = cnt - 1;

  int i0 = csr[start];
  int i1 = csr[start + min(1, last)];
  uint2 r0 = *(const uint2*)(xlb + (size_t)i0*128 + c0);
  uint2 r1 = *(const uint2*)(xlb + (size_t)i1*128 + c0);
  int ia = csr[start + min(2, last)];
  int ib = csr[start + min(3, last)];

  float m = -INFINITY, s = 0.f;
  float4 acc = make_float4(0.f, 0.f, 0.f, 0.f);

  for (int j = 0; j < cnt; j += 2){
    uint2 u0 = r0, u1 = r1;
    r0 = *(const uint2*)(xlb + (size_t)ia*128 + c0);
    r1 = *(const uint2*)(xlb + (size_t)ib*128 + c0);
    ia = csr[start + min(j + 4, last)];
    ib = csr[start + min(j + 5, last)];

    float v00 = bf2f((unsigned short)u0.x), v01 = bf2f((unsigned short)(u0.x >> 16));
    float v02 = bf2f((unsigned short)u0.y), v03 = bf2f((unsigned short)(u0.y >> 16));
    float v10 = bf2f((unsigned short)u1.x), v11 = bf2f((unsigned short)(u1.x >> 16));
    float v12 = bf2f((unsigned short)u1.y), v13 = bf2f((unsigned short)(u1.y >> 16));

    float g0, g1, g2, g3;
    g0 = v00 + xrv.x; g0 = fmaxf(g0, SLOPE*g0);
    g1 = v01 + xrv.y; g1 = fmaxf(g1, SLOPE*g1);
    g2 = v02 + xrv.z; g2 = fmaxf(g2, SLOPE*g2);
    g3 = v03 + xrv.w; g3 = fmaxf(g3, SLOPE*g3);
    float p0 = g0*av.x + g1*av.y + g2*av.z + g3*av.w;
    g0 = v10 + xrv.x; g0 = fmaxf(g0, SLOPE*g0);
    g1 = v11 + xrv.y; g1 = fmaxf(g1, SLOPE*g1);
    g2 = v12 + xrv.z; g2 = fmaxf(g2, SLOPE*g2);
    g3 = v13 + xrv.w; g3 = fmaxf(g3, SLOPE*g3);
    float p1 = g0*av.x + g1*av.y + g2*av.z + g3*av.w;

    p0 += __shfl_xor(p0, 1); p1 += __shfl_xor(p1, 1);
    p0 += __shfl_xor(p0, 2); p1 += __shfl_xor(p1, 2);
    p0 += __shfl_xor(p0, 4); p1 += __shfl_xor(p1, 4);
    if (j + 1 >= cnt) p1 = -INFINITY;   // tail edge contributes weight 0

    float pm = fmaxf(p0, p1);
    if (__any(pm > m + 8.f)){           // defer-max: rescale rarely
      float mn = fmaxf(m, pm);
      float sc = __expf(m - mn);
      s *= sc;
      acc.x *= sc; acc.y *= sc; acc.z *= sc; acc.w *= sc;
      m = mn;
    }
    float w0 = __expf(p0 - m);
    float w1 = __expf(p1 - m);
    s += w0 + w1;
    acc.x += w0*v00 + w1*v10;
    acc.y += w0*v01 + w1*v11;
    acc.z += w0*v02 + w1*v12;
    acc.w += w0*v03 + w1*v13;
  }

  float inv = 1.f/(s + 1e-16f);
  float4 b4 = *(const float4*)(bias + c0);
  float o[4];
  o[0] = acc.x*inv + b4.x;
  o[1] = acc.y*inv + b4.y;
  o[2] = acc.z*inv + b4.z;
  o[3] = acc.w*inv + b4.w;
  unsigned hh[4], hlv[4];
  #pragma unroll
  for (int j = 0; j < 4; ++j){
    float e = o[j] > 0.f ? o[j] : (__expf(o[j]) - 1.f);   // ELU
    hh[j]  = f2bf(e);
    hlv[j] = f2bf(e - bf2f((unsigned short)hh[j]));
  }
  *(uint2*)(Hh + (size_t)node*128 + c0) = make_uint2(hh[0]|(hh[1]<<16), hh[2]|(hh[3]<<16));
  *(uint2*)(Hl + (size_t)node*128 + c0) = make_uint2(hlv[0]|(hlv[1]<<16), hlv[2]|(hlv[3]<<16));
}

// ======================= Layer 2 aggregation (head-mean) =====================
__global__ __launch_bounds__(256) void k_agg2(
    const unsigned short* __restrict__ xlb, const float* __restrict__ xr,
    const int* __restrict__ rowptr, const int* __restrict__ deg,
    const int* __restrict__ csr, const float* __restrict__ att,
    const float* __restrict__ bias, float* __restrict__ out)
{
  int node = blockIdx.x*8 + (threadIdx.x >> 5);
  int hl   = threadIdx.x & 31;
  int h  = hl >> 3;
  int li = hl & 7;
  int c4 = h*40 + li*4;
  int cs = h*40 + 32 + li;

  float4 a4 = *(const float4*)(att + c4);
  float  as = att[cs];
  const float* xrp = xr + (size_t)node*160;
  float4 r4 = *(const float4*)(xrp + c4);
  float  rs = xrp[cs];

  int start = rowptr[node], cnt = deg[node];
  int last = cnt - 1;

  int i0 = csr[start];
  int i1 = csr[start + min(1, last)];
  uint2 rv0 = *(const uint2*)(xlb + (size_t)i0*160 + c4);
  unsigned short sv0 = xlb[(size_t)i0*160 + cs];
  uint2 rv1 = *(const uint2*)(xlb + (size_t)i1*160 + c4);
  unsigned short sv1 = xlb[(size_t)i1*160 + cs];
  int ia = csr[start + min(2, last)];
  int ib = csr[start + min(3, last)];

  float m = -INFINITY, s = 0.f;
  float4 ac4 = make_float4(0.f,0.f,0.f,0.f);
  float  acs = 0.f;

  for (int j = 0; j < cnt; j += 2){
    uint2 u0 = rv0, u1 = rv1;
    unsigned short t0 = sv0, t1 = sv1;
    rv0 = *(const uint2*)(xlb + (size_t)ia*160 + c4);
    sv0 = xlb[(size_t)ia*160 + cs];
    rv1 = *(const uint2*)(xlb + (size_t)ib*160 + c4);
    sv1 = xlb[(size_t)ib*160 + cs];
    ia = csr[start + min(j + 4, last)];
    ib = csr[start + min(j + 5, last)];

    float v00 = bf2f((unsigned short)u0.x), v01 = bf2f((unsigned short)(u0.x >> 16));
    float v02 = bf2f((unsigned short)u0.y), v03 = bf2f((unsigned short)(u0.y >> 16));
    float vs0 = bf2f(t0);
    float v10 = bf2f((unsigned short)u1.x), v11 = bf2f((unsigned short)(u1.x >> 16));
    float v12 = bf2f((unsigned short)u1.y), v13 = bf2f((unsigned short)(u1.y >> 16));
    float vs1 = bf2f(t1);

    float g0, g1, g2, g3, g4;
    g0 = v00 + r4.x; g0 = fmaxf(g0, SLOPE*g0);
    g1 = v01 + r4.y; g1 = fmaxf(g1, SLOPE*g1);
    g2 = v02 + r4.z; g2 = fmaxf(g2, SLOPE*g2);
    g3 = v03 + r4.w; g3 = fmaxf(g3, SLOPE*g3);
    g4 = vs0 + rs;   g4 = fmaxf(g4, SLOPE*g4);
    float p0 = g0*a4.x + g1*a4.y + g2*a4.z + g3*a4.w + g4*as;
    g0 = v10 + r4.x; g0 = fmaxf(g0, SLOPE*g0);
    g1 = v11 + r4.y; g1 = fmaxf(g1, SLOPE*g1);
    g2 = v12 + r4.z; g2 = fmaxf(g2, SLOPE*g2);
    g3 = v13 + r4.w; g3 = fmaxf(g3, SLOPE*g3);
    g4 = vs1 + rs;   g4 = fmaxf(g4, SLOPE*g4);
    float p1 = g0*a4.x + g1*a4.y + g2*a4.z + g3*a4.w + g4*as;

    p0 += __shfl_xor(p0, 1); p1 += __shfl_xor(p1, 1);
    p0 += __shfl_xor(p0, 2); p1 += __shfl_xor(p1, 2);
    p0 += __shfl_xor(p0, 4); p1 += __shfl_xor(p1, 4);
    if (j + 1 >= cnt) p1 = -INFINITY;

    float pm = fmaxf(p0, p1);
    if (__any(pm > m + 8.f)){
      float mn = fmaxf(m, pm);
      float sc = __expf(m - mn);
      s *= sc;
      ac4.x *= sc; ac4.y *= sc; ac4.z *= sc; ac4.w *= sc; acs *= sc;
      m = mn;
    }
    float w0 = __expf(p0 - m);
    float w1 = __expf(p1 - m);
    s += w0 + w1;
    ac4.x += w0*v00 + w1*v10;
    ac4.y += w0*v01 + w1*v11;
    ac4.z += w0*v02 + w1*v12;
    ac4.w += w0*v03 + w1*v13;
    acs   += w0*vs0 + w1*vs1;
  }

  float inv = 1.f/(s + 1e-16f);
  float o0 = ac4.x*inv, o1 = ac4.y*inv, o2 = ac4.z*inv, o3 = ac4.w*inv, o4 = acs*inv;
  o0 += __shfl_xor(o0, 8); o0 += __shfl_xor(o0, 16);
  o1 += __shfl_xor(o1, 8); o1 += __shfl_xor(o1, 16);
  o2 += __shfl_xor(o2, 8); o2 += __shfl_xor(o2, 16);
  o3 += __shfl_xor(o3, 8); o3 += __shfl_xor(o3, 16);
  o4 += __shfl_xor(o4, 8); o4 += __shfl_xor(o4, 16);
  if (h == 0){
    float4 b4 = *(const float4*)(bias + li*4);
    float4 r = make_float4(0.25f*o0 + b4.x, 0.25f*o1 + b4.y,
                           0.25f*o2 + b4.z, 0.25f*o3 + b4.w);
    *(float4*)(out + (size_t)node*OUTD + li*4) = r;
    out[(size_t)node*OUTD + 32 + li] = 0.25f*o4 + bias[32 + li];
  }
}

// ======================= launch =======================

extern "C" void kernel_launch(void* const* d_in, const int* in_sizes, int n_in,
                              void* d_out, int out_size, void* d_ws, size_t ws_size,
                              hipStream_t stream)
{
  const float* x     = (const float*)d_in[0];
  const int*   ei    = (const int*)  d_in[1];
  const float* Wl1   = (const float*)d_in[2];
  const float* bl1   = (const float*)d_in[3];
  const float* Wr1   = (const float*)d_in[4];
  const float* br1   = (const float*)d_in[5];
  const float* att1  = (const float*)d_in[6];
  const float* bias1 = (const float*)d_in[7];
  const float* Wl2   = (const float*)d_in[8];
  const float* bl2   = (const float*)d_in[9];
  const float* Wr2   = (const float*)d_in[10];
  const float* br2   = (const float*)d_in[11];
  const float* att2  = (const float*)d_in[12];
  const float* bias2 = (const float*)d_in[13];
  float* out = (float*)d_out;

  char* w = (char*)d_ws;
  size_t off = 0;
  auto alloc = [&](size_t bytes) -> void* {
    void* p = w + off;
    off = (off + bytes + 255) & ~(size_t)255;
    return p;
  };

  int* deg    = (int*)alloc((size_t)NNODES*4);
  int* rowptr = (int*)alloc((size_t)NNODES*4);
  int* bcount = (int*)alloc(512*4);
  int* bsum   = (int*)alloc(256*4);
  int* boff   = (int*)alloc(256*4);
  int* csr    = (int*)alloc((size_t)ET*4);
  unsigned short* xlbuf = (unsigned short*)alloc((size_t)NNODES*160*2); // bf16 xl rows
  float* xrbuf = (float*)alloc((size_t)NNODES*160*4);                   // f32 xr rows
  unsigned short* Xh = (unsigned short*)alloc((size_t)NNODES*256*2);    // later Hh
  unsigned short* Xl = (unsigned short*)alloc((size_t)NNODES*256*2);    // later Hl
  unsigned short* W1th = (unsigned short*)alloc((size_t)256*256*2);
  unsigned short* W1tl = (unsigned short*)alloc((size_t)256*256*2);
  unsigned short* W2th = (unsigned short*)alloc((size_t)320*128*2);
  unsigned short* W2tl = (unsigned short*)alloc((size_t)320*128*2);
  unsigned short* Hh = Xh;   // reuse: X splits dead after gemm1
  unsigned short* Hl = Xl;
  // pairs buffer (12.8 MB) aliases Xh (25.6 MB): dead before k_split_x writes it
  uint2* pairs = (uint2*)Xh;

  const int NB = (NNODES + 255)/256;         // 196

  // CSR (bucketed build: no full-size atomics, locality-confined writes)
  hipMemsetAsync(bcount, 0, 512*4, stream);
  k_part    <<<256, 256, 0, stream>>>(ei, bcount, pairs);
  k_bdeg    <<<NBUCK, 256, 0, stream>>>(bcount, pairs, deg);
  k_bsum    <<<NB, 256, 0, stream>>>(deg, bsum);
  k_scanb   <<<1, 256, 0, stream>>>(bsum, NB, boff);
  k_scanw   <<<NB, 256, 0, stream>>>(deg, boff, rowptr);
  k_bscatter<<<NBUCK, 256, 0, stream>>>(bcount, pairs, rowptr, csr);

  // splits
  k_split_x<<<(NNODES*256/8 + 255)/256, 256, 0, stream>>>(x, Xh, Xl, NNODES*256/8);
  k_split_wt<<<(256*32 + 255)/256, 256, 0, stream>>>(Wl1, Wr1, 128, 256, 256, W1th, W1tl);
  k_split_wt<<<(320*16 + 255)/256, 256, 0, stream>>>(Wl2, Wr2, 160, 128, 320, W2th, W2tl);

  // layer 1
  dim3 g1((NNODES + 127)/128, 2);   // N=256
  k_gemm_mfma<<<g1, 256, 0, stream>>>(Xh, Xl, 256, NNODES,
                                      W1th, W1tl, 256, 128,
                                      bl1, br1, xlbuf, xrbuf, 128);
  k_agg1<<<6250, 256, 0, stream>>>(xlbuf, xrbuf, rowptr, deg, csr, att1, bias1, Hh, Hl);

  // layer 2
  dim3 g2((NNODES + 127)/128, 3);   // N=320 (last block half-masked)
  k_gemm_mfma<<<g2, 256, 0, stream>>>(Hh, Hl, 128, NNODES,
                                      W2th, W2tl, 320, 160,
                                      bl2, br2, xlbuf, xrbuf, 160);
  k_agg2<<<NNODES/8, 256, 0, stream>>>(xlbuf, xrbuf, rowptr, deg, csr, att2, bias2, out);
}